// Round 6
// baseline (364.128 us; speedup 1.0000x reference)
//
#include <hip/hip_runtime.h>

#define FDIM 128
#define LN_EPS 1e-5f

typedef short short8 __attribute__((ext_vector_type(8)));
typedef float f32x4 __attribute__((ext_vector_type(4)));

__device__ __forceinline__ ushort f2bf(float f) {
    uint u = __float_as_uint(f);
    u += 0x7fff + ((u >> 16) & 1);      // RNE
    return (ushort)(u >> 16);
}
__device__ __forceinline__ float bflo(uint u) { return __uint_as_float(u << 16); }
__device__ __forceinline__ float bfhi(uint u) { return __uint_as_float(u & 0xffff0000u); }

// ---------------- CSR build (exact region; no pos array) ----------------
__global__ void k_count(const int* __restrict__ dst, int* __restrict__ cnt, int E) {
    int e = blockIdx.x * 256 + threadIdx.x;
    if (e < E) atomicAdd(&cnt[dst[e]], 1);
}

__global__ __launch_bounds__(1024) void k_scan_block(const int* __restrict__ cnt,
                                                     int* __restrict__ rowptr,
                                                     int* __restrict__ partial, int N) {
    __shared__ int s[1024];
    int t = threadIdx.x;
    int i = blockIdx.x * 1024 + t;
    int v = (i < N) ? cnt[i] : 0;
    s[t] = v;
    __syncthreads();
    for (int off = 1; off < 1024; off <<= 1) {
        int u = (t >= off) ? s[t - off] : 0;
        __syncthreads();
        s[t] += u;
        __syncthreads();
    }
    if (i < N) rowptr[i] = s[t] - v;
    if (t == 1023) partial[blockIdx.x] = s[1023];
}

__global__ __launch_bounds__(1024) void k_scan_partial(int* __restrict__ partial, int NB) {
    __shared__ int s[1024];
    int t = threadIdx.x;
    int v = (t < NB) ? partial[t] : 0;
    s[t] = v;
    __syncthreads();
    for (int off = 1; off < 1024; off <<= 1) {
        int u = (t >= off) ? s[t - off] : 0;
        __syncthreads();
        s[t] += u;
        __syncthreads();
    }
    if (t < NB) partial[t] = s[t] - v;
}

__global__ void k_finalize(int* __restrict__ rowptr, const int* __restrict__ partial,
                           const int* __restrict__ cnt, float* __restrict__ dinv,
                           int N, int E) {
    int i = blockIdx.x * 256 + threadIdx.x;
    if (i < N) {
        rowptr[i] += partial[i >> 10];
        dinv[i] = rsqrtf((float)cnt[i] + 1.0f);
    }
    if (i == 0) rowptr[N] = E;
}

// second atomic pass assigns slots (order within bucket is arbitrary -> sum order only)
__global__ void k_fill(const int* __restrict__ src, const int* __restrict__ dst,
                       const int* __restrict__ rowptr, int* __restrict__ cnt2,
                       int* __restrict__ col, int E) {
    int e = blockIdx.x * 256 + threadIdx.x;
    if (e < E) {
        int d = dst[e];
        int slot = atomicAdd(&cnt2[d], 1);
        col[rowptr[d] + slot] = src[e];
    }
    if (e < 8) col[E + e] = 0;           // slack (always clamped in agg tail anyway)
}

// ---------------- W[128,128] fp32 -> W^T bf16 (both weights, one launch) ----------------
__global__ void k_wt2(const float* __restrict__ W1, const float* __restrict__ W2,
                      ushort* __restrict__ WT1, ushort* __restrict__ WT2) {
    int b = blockIdx.x, k = threadIdx.x;
    if (b < 128) WT1[b * 128 + k] = f2bf(W1[k * 128 + b]);
    else         WT2[(b - 128) * 128 + k] = f2bf(W2[k * 128 + (b - 128)]);
}

// -------- MFMA GEMM: H'[r] = dinv[r] * (X[r,:] @ W)  (bf16 out, pre-scaled) --------
// X and W both staged in LDS with XOR swizzle; mfma(a=W-col frag, b=X-row frag):
// lane holds out row r=lane&15, cols (lane>>4)*4+reg => 8B stores.
template <bool F32IN>
__global__ __launch_bounds__(256) void k_gemm(const void* __restrict__ Xin,
                                              const ushort* __restrict__ WT,
                                              const float* __restrict__ dinv,
                                              ushort* __restrict__ H, int N) {
    __shared__ ushort sX[64 * 128];      // 16 KB
    __shared__ ushort sW[128 * 128];     // 32 KB
    char* sXb = (char*)sX;
    char* sWb = (char*)sW;

    int t = threadIdx.x;
    int w = t >> 6, lane = t & 63;
    int cl = lane & 15, kq = lane >> 4;
    int base = blockIdx.x * 64;

    // ---- stage W^T (rows c=0..127 of 256B, swizzled) ----
    const short8* Wg = (const short8*)WT;
#pragma unroll
    for (int k = 0; k < 8; ++k) {
        int idx = t + k * 256;                        // 0..2047 short8s
        int c = idx >> 4, ch = idx & 15;
        *(short8*)(sWb + c * 256 + ((ch * 16) ^ ((c & 7) << 4))) = Wg[idx];
    }

    // ---- stage X tile (rows base..base+63) ----
    if constexpr (F32IN) {
        const float4* X4 = (const float4*)Xin;
        size_t lim = (size_t)N * 32 - 1;
#pragma unroll
        for (int k = 0; k < 8; ++k) {
            int idx = t + k * 256;                    // 64 rows x 32 f4
            size_t gi = (size_t)base * 32 + idx;
            float4 v = X4[gi < lim ? gi : lim];
            ushort4 o;
            o.x = f2bf(v.x); o.y = f2bf(v.y); o.z = f2bf(v.z); o.w = f2bf(v.w);
            int row = idx >> 5, b8 = (idx & 31) * 8;
            *(ushort4*)(sXb + row * 256 + (b8 ^ ((row & 7) << 4))) = o;
        }
    } else {
        const short8* X8 = (const short8*)Xin;
        size_t lim = (size_t)N * 16 - 1;
#pragma unroll
        for (int k = 0; k < 4; ++k) {
            int idx = t + k * 256;                    // 64 rows x 16 s8
            size_t gi = (size_t)base * 16 + idx;
            short8 v = X8[gi < lim ? gi : lim];
            int row = idx >> 4, b16 = (idx & 15) * 16;
            *(short8*)(sXb + row * 256 + (b16 ^ ((row & 7) << 4))) = v;
        }
    }
    __syncthreads();

    // ---- X fragments ----
    int rl = w * 16 + cl;
    short8 b0, b1, b2, b3;
#pragma unroll
    for (int kt = 0; kt < 4; ++kt) {
        short8 v = *(const short8*)(sXb + rl * 256 + ((kt * 64 + kq * 16) ^ ((rl & 7) << 4)));
        if (kt == 0) b0 = v; else if (kt == 1) b1 = v; else if (kt == 2) b2 = v; else b3 = v;
    }

    int r = base + rl;
    bool ok = r < N;
    float di = dinv[min(r, N - 1)];
#pragma unroll
    for (int nt = 0; nt < 8; ++nt) {
        int c = nt * 16 + cl;                          // WT row = W col
        int sw = (c & 7) << 4;
        f32x4 acc = {0.f, 0.f, 0.f, 0.f};
        acc = __builtin_amdgcn_mfma_f32_16x16x32_bf16(
            *(const short8*)(sWb + c * 256 + ((0 * 64 + kq * 16) ^ sw)), b0, acc, 0, 0, 0);
        acc = __builtin_amdgcn_mfma_f32_16x16x32_bf16(
            *(const short8*)(sWb + c * 256 + ((1 * 64 + kq * 16) ^ sw)), b1, acc, 0, 0, 0);
        acc = __builtin_amdgcn_mfma_f32_16x16x32_bf16(
            *(const short8*)(sWb + c * 256 + ((2 * 64 + kq * 16) ^ sw)), b2, acc, 0, 0, 0);
        acc = __builtin_amdgcn_mfma_f32_16x16x32_bf16(
            *(const short8*)(sWb + c * 256 + ((3 * 64 + kq * 16) ^ sw)), b3, acc, 0, 0, 0);
        if (ok) {
            ushort4 o;
            o.x = f2bf(acc[0] * di); o.y = f2bf(acc[1] * di);
            o.z = f2bf(acc[2] * di); o.w = f2bf(acc[3] * di);
            *(ushort4*)(H + (size_t)r * 128 + nt * 16 + kq * 4) = o;
        }
    }
}

// ------- aggregate(pre-scaled bf16 h') + bias + ReLU + LN; 1 node/wave -------
// per edge: gather + unpack + add only (dinv folded into h'); tail clamps to zero row N.
__global__ __launch_bounds__(256) void k_agg(const uint* __restrict__ H,   // (N+1) rows
                                             const int* __restrict__ rowptr,
                                             const int* __restrict__ col,
                                             const float* __restrict__ dinv,
                                             const float* __restrict__ bias,
                                             const float* __restrict__ gamma,
                                             const float* __restrict__ beta,
                                             float* __restrict__ outf,
                                             uint* __restrict__ outb,
                                             int N) {
    int wave = threadIdx.x >> 6;
    int lane = threadIdx.x & 63;
    int node = blockIdx.x * 4 + wave;
    if (node >= N) return;

    float di = dinv[node];
    uint hs = H[(size_t)node * 64 + lane];
    float ax = bflo(hs);                  // h'[self] = di*h[self]
    float ay = bfhi(hs);

    int beg = rowptr[node];
    int deg = rowptr[node + 1] - beg;
    const int* cp = col + beg;

    for (int i = 0; i < deg; i += 8) {
        int s0 = cp[i + 0], s1 = cp[i + 1], s2 = cp[i + 2], s3 = cp[i + 3];
        int s4 = cp[i + 4], s5 = cp[i + 5], s6 = cp[i + 6], s7 = cp[i + 7];
        s0 = (i + 0 < deg) ? s0 : N;      // row N is all-zero
        s1 = (i + 1 < deg) ? s1 : N;
        s2 = (i + 2 < deg) ? s2 : N;
        s3 = (i + 3 < deg) ? s3 : N;
        s4 = (i + 4 < deg) ? s4 : N;
        s5 = (i + 5 < deg) ? s5 : N;
        s6 = (i + 6 < deg) ? s6 : N;
        s7 = (i + 7 < deg) ? s7 : N;
        uint u0 = H[(size_t)s0 * 64 + lane];
        uint u1 = H[(size_t)s1 * 64 + lane];
        uint u2 = H[(size_t)s2 * 64 + lane];
        uint u3 = H[(size_t)s3 * 64 + lane];
        uint u4 = H[(size_t)s4 * 64 + lane];
        uint u5 = H[(size_t)s5 * 64 + lane];
        uint u6 = H[(size_t)s6 * 64 + lane];
        uint u7 = H[(size_t)s7 * 64 + lane];
        ax += bflo(u0); ay += bfhi(u0);
        ax += bflo(u1); ay += bfhi(u1);
        ax += bflo(u2); ay += bfhi(u2);
        ax += bflo(u3); ay += bfhi(u3);
        ax += bflo(u4); ay += bfhi(u4);
        ax += bflo(u5); ay += bfhi(u5);
        ax += bflo(u6); ay += bfhi(u6);
        ax += bflo(u7); ay += bfhi(u7);
    }

    float2 bb = ((const float2*)bias)[lane];
    float a0 = fmaxf(fmaf(ax, di, bb.x), 0.f);
    float a1 = fmaxf(fmaf(ay, di, bb.y), 0.f);

    float s1 = a0 + a1;
    float s2 = a0 * a0 + a1 * a1;
#pragma unroll
    for (int off = 32; off >= 1; off >>= 1) {
        s1 += __shfl_xor(s1, off);
        s2 += __shfl_xor(s2, off);
    }
    float mu = s1 * (1.f / 128.f);
    float var = s2 * (1.f / 128.f) - mu * mu;
    float rs = rsqrtf(var + LN_EPS);

    float2 g = ((const float2*)gamma)[lane];
    float2 be = ((const float2*)beta)[lane];
    float o0 = (a0 - mu) * rs * g.x + be.x;
    float o1 = (a1 - mu) * rs * g.y + be.y;
    if (outf) {
        ((float2*)outf)[(size_t)node * 64 + lane] = make_float2(o0, o1);
    } else {
        outb[(size_t)node * 64 + lane] = (uint)f2bf(o0) | ((uint)f2bf(o1) << 16);
    }
}

// ---------------- launch ----------------
extern "C" void kernel_launch(void* const* d_in, const int* in_sizes, int n_in,
                              void* d_out, int out_size, void* d_ws, size_t ws_size,
                              hipStream_t stream) {
    const float* x  = (const float*)d_in[0];
    const int*   ei = (const int*)d_in[1];
    const float* W1 = (const float*)d_in[2];
    const float* b1 = (const float*)d_in[3];
    const float* W2 = (const float*)d_in[4];
    const float* b2 = (const float*)d_in[5];
    const float* g1 = (const float*)d_in[6];
    const float* be1 = (const float*)d_in[7];
    const float* g2 = (const float*)d_in[8];
    const float* be2 = (const float*)d_in[9];

    int N = in_sizes[0] / FDIM;
    int E = in_sizes[1] / 2;
    const int* srcp = ei;
    const int* dstp = ei + E;
    float* out = (float*)d_out;

    char* w = (char*)d_ws;
    size_t off = 0;
    auto take = [&](size_t bytes) {
        void* p = w + off;
        off = (off + bytes + 255) & ~(size_t)255;
        return p;
    };
    ushort* hb   = (ushort*)take((size_t)(N + 1) * FDIM * sizeof(ushort)); // h' + zero row N
    ushort* WT1  = (ushort*)take(128 * 128 * sizeof(ushort));
    ushort* WT2  = (ushort*)take(128 * 128 * sizeof(ushort));
    int* cnt     = (int*)take((size_t)N * sizeof(int));       // adjacent:
    int* cnt2    = (int*)take((size_t)N * sizeof(int));       //   cnt,cnt2 share one memset
    int* rowptr  = (int*)take((size_t)(N + 1) * sizeof(int));
    int* colb    = (int*)take((size_t)(E + 8) * sizeof(int));
    float* dinv  = (float*)take((size_t)N * sizeof(float));
    int* partial = (int*)take(1024 * sizeof(int));
    (void)ws_size;

    int NB = (N + 1023) >> 10;

    // zero: cnt + cnt2 (contiguous modulo 256B pad -> memset the whole span), zero row of hb
    hipMemsetAsync(cnt, 0, (size_t)((char*)rowptr - (char*)cnt), stream);
    hipMemsetAsync(hb + (size_t)N * FDIM, 0, FDIM * sizeof(ushort), stream);

    // CSR build
    k_count<<<(E + 255) / 256, 256, 0, stream>>>(dstp, cnt, E);
    k_scan_block<<<NB, 1024, 0, stream>>>(cnt, rowptr, partial, N);
    k_scan_partial<<<1, 1024, 0, stream>>>(partial, NB);
    k_finalize<<<(N + 255) / 256, 256, 0, stream>>>(rowptr, partial, cnt, dinv, N, E);
    k_fill<<<(E + 255) / 256, 256, 0, stream>>>(srcp, dstp, rowptr, cnt2, colb, E);

    // weights -> W^T bf16
    k_wt2<<<256, 128, 0, stream>>>(W1, W2, WT1, WT2);

    // layer 1: gemm (fp32 in, convert + dinv-scale fused) -> agg (bf16 out into d_out)
    k_gemm<true><<<(N + 63) / 64, 256, 0, stream>>>(x, WT1, dinv, hb, N);
    k_agg<<<(N + 3) / 4, 256, 0, stream>>>((const uint*)hb, rowptr, colb, dinv,
                                           b1, g1, be1, nullptr, (uint*)d_out, N);
    // layer 2: gemm reads bf16 from d_out, agg writes final fp32 d_out
    k_gemm<false><<<(N + 63) / 64, 256, 0, stream>>>(d_out, WT2, dinv, hb, N);
    k_agg<<<(N + 3) / 4, 256, 0, stream>>>((const uint*)hb, rowptr, colb, dinv,
                                           b2, g2, be2, out, nullptr, N);
}

// Round 7
// 278.288 us; speedup vs baseline: 1.3085x; 1.3085x over previous
//
#include <hip/hip_runtime.h>

#define FDIM 128
#define LN_EPS 1e-5f

typedef short short8 __attribute__((ext_vector_type(8)));
typedef float f32x4 __attribute__((ext_vector_type(4)));

__device__ __forceinline__ ushort f2bf(float f) {
    uint u = __float_as_uint(f);
    u += 0x7fff + ((u >> 16) & 1);      // RNE
    return (ushort)(u >> 16);
}
__device__ __forceinline__ float bflo(uint u) { return __uint_as_float(u << 16); }
__device__ __forceinline__ float bfhi(uint u) { return __uint_as_float(u & 0xffff0000u); }

// ---------------- CSR build (R5 structure: count+pos, fill reads pos) ----------------
__global__ void k_count(const int* __restrict__ dst, int* __restrict__ cnt,
                        int* __restrict__ pos, int E) {
    int e = blockIdx.x * 256 + threadIdx.x;
    if (e < E) pos[e] = atomicAdd(&cnt[dst[e]], 1);
}

__global__ __launch_bounds__(1024) void k_scan_block(const int* __restrict__ cnt,
                                                     int* __restrict__ rowptr,
                                                     int* __restrict__ partial, int N) {
    __shared__ int s[1024];
    int t = threadIdx.x;
    int i = blockIdx.x * 1024 + t;
    int v = (i < N) ? cnt[i] : 0;
    s[t] = v;
    __syncthreads();
    for (int off = 1; off < 1024; off <<= 1) {
        int u = (t >= off) ? s[t - off] : 0;
        __syncthreads();
        s[t] += u;
        __syncthreads();
    }
    if (i < N) rowptr[i] = s[t] - v;
    if (t == 1023) partial[blockIdx.x] = s[1023];
}

__global__ __launch_bounds__(1024) void k_scan_partial(int* __restrict__ partial, int NB) {
    __shared__ int s[1024];
    int t = threadIdx.x;
    int v = (t < NB) ? partial[t] : 0;
    s[t] = v;
    __syncthreads();
    for (int off = 1; off < 1024; off <<= 1) {
        int u = (t >= off) ? s[t - off] : 0;
        __syncthreads();
        s[t] += u;
        __syncthreads();
    }
    if (t < NB) partial[t] = s[t] - v;
}

__global__ void k_finalize(int* __restrict__ rowptr, const int* __restrict__ partial,
                           const int* __restrict__ cnt, float* __restrict__ dinv,
                           int N, int E) {
    int i = blockIdx.x * 256 + threadIdx.x;
    if (i < N) {
        rowptr[i] += partial[i >> 10];
        dinv[i] = rsqrtf((float)cnt[i] + 1.0f);
    }
    if (i == 0) rowptr[N] = E;
}

__global__ void k_fill(const int* __restrict__ src, const int* __restrict__ dst,
                       const int* __restrict__ rowptr, const int* __restrict__ pos,
                       int* __restrict__ col, int E) {
    int e = blockIdx.x * 256 + threadIdx.x;
    if (e < E) col[rowptr[dst[e]] + pos[e]] = src[e];
    if (e < 8) col[E + e] = 0;           // slack so agg's unroll-8 tail reads valid ids
}

// ---------------- W[128,128] fp32 -> W^T bf16 (both weights, one launch) ----------------
__global__ void k_wt2(const float* __restrict__ W1, const float* __restrict__ W2,
                      ushort* __restrict__ WT1, ushort* __restrict__ WT2) {
    int b = blockIdx.x, k = threadIdx.x;
    if (b < 128) WT1[b * 128 + k] = f2bf(W1[k * 128 + b]);
    else         WT2[(b - 128) * 128 + k] = f2bf(W2[k * 128 + (b - 128)]);
}

// -------- MFMA GEMM: H'[r] = dinv[r] * (X[r,:] @ W)  (bf16 out, pre-scaled) --------
// X and W both staged in LDS with XOR swizzle; mfma(a=W-col frag, b=X-row frag):
// lane holds out row r=lane&15, cols (lane>>4)*4+reg => 8B stores.
template <bool F32IN>
__global__ __launch_bounds__(256) void k_gemm(const void* __restrict__ Xin,
                                              const ushort* __restrict__ WT,
                                              const float* __restrict__ dinv,
                                              ushort* __restrict__ H, int N) {
    __shared__ ushort sX[64 * 128];      // 16 KB
    __shared__ ushort sW[128 * 128];     // 32 KB
    char* sXb = (char*)sX;
    char* sWb = (char*)sW;

    int t = threadIdx.x;
    int w = t >> 6, lane = t & 63;
    int cl = lane & 15, kq = lane >> 4;
    int base = blockIdx.x * 64;

    // ---- stage W^T (rows c=0..127 of 256B, swizzled) ----
    const short8* Wg = (const short8*)WT;
#pragma unroll
    for (int k = 0; k < 8; ++k) {
        int idx = t + k * 256;                        // 0..2047 short8s
        int c = idx >> 4, ch = idx & 15;
        *(short8*)(sWb + c * 256 + ((ch * 16) ^ ((c & 7) << 4))) = Wg[idx];
    }

    // ---- stage X tile (rows base..base+63) ----
    if constexpr (F32IN) {
        const float4* X4 = (const float4*)Xin;
        size_t lim = (size_t)N * 32 - 1;
#pragma unroll
        for (int k = 0; k < 8; ++k) {
            int idx = t + k * 256;                    // 64 rows x 32 f4
            size_t gi = (size_t)base * 32 + idx;
            float4 v = X4[gi < lim ? gi : lim];
            ushort4 o;
            o.x = f2bf(v.x); o.y = f2bf(v.y); o.z = f2bf(v.z); o.w = f2bf(v.w);
            int row = idx >> 5, b8 = (idx & 31) * 8;
            *(ushort4*)(sXb + row * 256 + (b8 ^ ((row & 7) << 4))) = o;
        }
    } else {
        const short8* X8 = (const short8*)Xin;
        size_t lim = (size_t)N * 16 - 1;
#pragma unroll
        for (int k = 0; k < 4; ++k) {
            int idx = t + k * 256;                    // 64 rows x 16 s8
            size_t gi = (size_t)base * 16 + idx;
            short8 v = X8[gi < lim ? gi : lim];
            int row = idx >> 4, b16 = (idx & 15) * 16;
            *(short8*)(sXb + row * 256 + (b16 ^ ((row & 7) << 4))) = v;
        }
    }
    __syncthreads();

    // ---- X fragments ----
    int rl = w * 16 + cl;
    short8 b0, b1, b2, b3;
#pragma unroll
    for (int kt = 0; kt < 4; ++kt) {
        short8 v = *(const short8*)(sXb + rl * 256 + ((kt * 64 + kq * 16) ^ ((rl & 7) << 4)));
        if (kt == 0) b0 = v; else if (kt == 1) b1 = v; else if (kt == 2) b2 = v; else b3 = v;
    }

    int r = base + rl;
    bool ok = r < N;
    float di = dinv[min(r, N - 1)];
#pragma unroll
    for (int nt = 0; nt < 8; ++nt) {
        int c = nt * 16 + cl;                          // WT row = W col
        int sw = (c & 7) << 4;
        f32x4 acc = {0.f, 0.f, 0.f, 0.f};
        acc = __builtin_amdgcn_mfma_f32_16x16x32_bf16(
            *(const short8*)(sWb + c * 256 + ((0 * 64 + kq * 16) ^ sw)), b0, acc, 0, 0, 0);
        acc = __builtin_amdgcn_mfma_f32_16x16x32_bf16(
            *(const short8*)(sWb + c * 256 + ((1 * 64 + kq * 16) ^ sw)), b1, acc, 0, 0, 0);
        acc = __builtin_amdgcn_mfma_f32_16x16x32_bf16(
            *(const short8*)(sWb + c * 256 + ((2 * 64 + kq * 16) ^ sw)), b2, acc, 0, 0, 0);
        acc = __builtin_amdgcn_mfma_f32_16x16x32_bf16(
            *(const short8*)(sWb + c * 256 + ((3 * 64 + kq * 16) ^ sw)), b3, acc, 0, 0, 0);
        if (ok) {
            ushort4 o;
            o.x = f2bf(acc[0] * di); o.y = f2bf(acc[1] * di);
            o.z = f2bf(acc[2] * di); o.w = f2bf(acc[3] * di);
            *(ushort4*)(H + (size_t)r * 128 + nt * 16 + kq * 4) = o;
        }
    }
}

// ------- aggregate(pre-scaled bf16 h') + bias + ReLU + LN; 1 node/wave -------
// per edge: gather + unpack + add only (dinv folded into h'); tail clamps to zero row N.
__global__ __launch_bounds__(256) void k_agg(const uint* __restrict__ H,   // (N+1) rows
                                             const int* __restrict__ rowptr,
                                             const int* __restrict__ col,
                                             const float* __restrict__ dinv,
                                             const float* __restrict__ bias,
                                             const float* __restrict__ gamma,
                                             const float* __restrict__ beta,
                                             float* __restrict__ outf,
                                             uint* __restrict__ outb,
                                             int N) {
    int wave = threadIdx.x >> 6;
    int lane = threadIdx.x & 63;
    int node = blockIdx.x * 4 + wave;
    if (node >= N) return;

    float di = dinv[node];
    uint hs = H[(size_t)node * 64 + lane];
    float ax = bflo(hs);                  // h'[self] = di*h[self]
    float ay = bfhi(hs);

    int beg = rowptr[node];
    int deg = rowptr[node + 1] - beg;
    const int* cp = col + beg;

    for (int i = 0; i < deg; i += 8) {
        int s0 = cp[i + 0], s1 = cp[i + 1], s2 = cp[i + 2], s3 = cp[i + 3];
        int s4 = cp[i + 4], s5 = cp[i + 5], s6 = cp[i + 6], s7 = cp[i + 7];
        s0 = (i + 0 < deg) ? s0 : N;      // row N is all-zero
        s1 = (i + 1 < deg) ? s1 : N;
        s2 = (i + 2 < deg) ? s2 : N;
        s3 = (i + 3 < deg) ? s3 : N;
        s4 = (i + 4 < deg) ? s4 : N;
        s5 = (i + 5 < deg) ? s5 : N;
        s6 = (i + 6 < deg) ? s6 : N;
        s7 = (i + 7 < deg) ? s7 : N;
        uint u0 = H[(size_t)s0 * 64 + lane];
        uint u1 = H[(size_t)s1 * 64 + lane];
        uint u2 = H[(size_t)s2 * 64 + lane];
        uint u3 = H[(size_t)s3 * 64 + lane];
        uint u4 = H[(size_t)s4 * 64 + lane];
        uint u5 = H[(size_t)s5 * 64 + lane];
        uint u6 = H[(size_t)s6 * 64 + lane];
        uint u7 = H[(size_t)s7 * 64 + lane];
        ax += bflo(u0); ay += bfhi(u0);
        ax += bflo(u1); ay += bfhi(u1);
        ax += bflo(u2); ay += bfhi(u2);
        ax += bflo(u3); ay += bfhi(u3);
        ax += bflo(u4); ay += bfhi(u4);
        ax += bflo(u5); ay += bfhi(u5);
        ax += bflo(u6); ay += bfhi(u6);
        ax += bflo(u7); ay += bfhi(u7);
    }

    float2 bb = ((const float2*)bias)[lane];
    float a0 = fmaxf(fmaf(ax, di, bb.x), 0.f);
    float a1 = fmaxf(fmaf(ay, di, bb.y), 0.f);

    float s1 = a0 + a1;
    float s2 = a0 * a0 + a1 * a1;
#pragma unroll
    for (int off = 32; off >= 1; off >>= 1) {
        s1 += __shfl_xor(s1, off);
        s2 += __shfl_xor(s2, off);
    }
    float mu = s1 * (1.f / 128.f);
    float var = s2 * (1.f / 128.f) - mu * mu;
    float rs = rsqrtf(var + LN_EPS);

    float2 g = ((const float2*)gamma)[lane];
    float2 be = ((const float2*)beta)[lane];
    float o0 = (a0 - mu) * rs * g.x + be.x;
    float o1 = (a1 - mu) * rs * g.y + be.y;
    if (outf) {
        ((float2*)outf)[(size_t)node * 64 + lane] = make_float2(o0, o1);
    } else {
        outb[(size_t)node * 64 + lane] = (uint)f2bf(o0) | ((uint)f2bf(o1) << 16);
    }
}

// ---------------- launch ----------------
extern "C" void kernel_launch(void* const* d_in, const int* in_sizes, int n_in,
                              void* d_out, int out_size, void* d_ws, size_t ws_size,
                              hipStream_t stream) {
    const float* x  = (const float*)d_in[0];
    const int*   ei = (const int*)d_in[1];
    const float* W1 = (const float*)d_in[2];
    const float* b1 = (const float*)d_in[3];
    const float* W2 = (const float*)d_in[4];
    const float* b2 = (const float*)d_in[5];
    const float* g1 = (const float*)d_in[6];
    const float* be1 = (const float*)d_in[7];
    const float* g2 = (const float*)d_in[8];
    const float* be2 = (const float*)d_in[9];

    int N = in_sizes[0] / FDIM;
    int E = in_sizes[1] / 2;
    const int* srcp = ei;
    const int* dstp = ei + E;
    float* out = (float*)d_out;

    char* w = (char*)d_ws;
    size_t off = 0;
    auto take = [&](size_t bytes) {
        void* p = w + off;
        off = (off + bytes + 255) & ~(size_t)255;
        return p;
    };
    ushort* hb   = (ushort*)take((size_t)(N + 1) * FDIM * sizeof(ushort)); // h' + zero row N
    ushort* WT1  = (ushort*)take(128 * 128 * sizeof(ushort));
    ushort* WT2  = (ushort*)take(128 * 128 * sizeof(ushort));
    int* cnt     = (int*)take((size_t)N * sizeof(int));
    int* rowptr  = (int*)take((size_t)(N + 1) * sizeof(int));
    int* pos     = (int*)take((size_t)E * sizeof(int));
    int* colb    = (int*)take((size_t)(E + 8) * sizeof(int));
    float* dinv  = (float*)take((size_t)N * sizeof(float));
    int* partial = (int*)take(1024 * sizeof(int));
    (void)ws_size;

    int NB = (N + 1023) >> 10;

    // zero cnt (memset), zero slack row N of hb
    hipMemsetAsync(cnt, 0, (size_t)N * sizeof(int), stream);
    hipMemsetAsync(hb + (size_t)N * FDIM, 0, FDIM * sizeof(ushort), stream);

    // CSR build (shared by both layers)
    k_count<<<(E + 255) / 256, 256, 0, stream>>>(dstp, cnt, pos, E);
    k_scan_block<<<NB, 1024, 0, stream>>>(cnt, rowptr, partial, N);
    k_scan_partial<<<1, 1024, 0, stream>>>(partial, NB);
    k_finalize<<<(N + 255) / 256, 256, 0, stream>>>(rowptr, partial, cnt, dinv, N, E);
    k_fill<<<(E + 255) / 256, 256, 0, stream>>>(srcp, dstp, rowptr, pos, colb, E);

    // weights -> W^T bf16
    k_wt2<<<256, 128, 0, stream>>>(W1, W2, WT1, WT2);

    // layer 1: gemm (fp32 in, convert + dinv-scale fused) -> agg (bf16 out into d_out)
    k_gemm<true><<<(N + 63) / 64, 256, 0, stream>>>(x, WT1, dinv, hb, N);
    k_agg<<<(N + 3) / 4, 256, 0, stream>>>((const uint*)hb, rowptr, colb, dinv,
                                           b1, g1, be1, nullptr, (uint*)d_out, N);
    // layer 2: gemm reads bf16 from d_out, agg writes final fp32 d_out
    k_gemm<false><<<(N + 63) / 64, 256, 0, stream>>>(d_out, WT2, dinv, hb, N);
    k_agg<<<(N + 3) / 4, 256, 0, stream>>>((const uint*)hb, rowptr, colb, dinv,
                                           b2, g2, be2, out, nullptr, N);
}

// Round 8
// 269.604 us; speedup vs baseline: 1.3506x; 1.0322x over previous
//
#include <hip/hip_runtime.h>

#define FDIM 128
#define LN_EPS 1e-5f

typedef short short8 __attribute__((ext_vector_type(8)));
typedef float f32x4 __attribute__((ext_vector_type(4)));

__device__ __forceinline__ ushort f2bf(float f) {
    uint u = __float_as_uint(f);
    u += 0x7fff + ((u >> 16) & 1);      // RNE
    return (ushort)(u >> 16);
}
__device__ __forceinline__ float bflo(uint u) { return __uint_as_float(u << 16); }
__device__ __forceinline__ float bfhi(uint u) { return __uint_as_float(u & 0xffff0000u); }

// ---------------- CSR build (pad-8 rows; count+pos, fill reads pos) ----------------
__global__ void k_count(const int* __restrict__ dst, int* __restrict__ cnt,
                        int* __restrict__ pos, int E) {
    int e = blockIdx.x * 256 + threadIdx.x;
    if (e < E) pos[e] = atomicAdd(&cnt[dst[e]], 1);
}

// scan over ROUNDED counts -> rowptr8
__global__ __launch_bounds__(1024) void k_scan_block(const int* __restrict__ cnt,
                                                     int* __restrict__ rowptr,
                                                     int* __restrict__ partial, int N) {
    __shared__ int s[1024];
    int t = threadIdx.x;
    int i = blockIdx.x * 1024 + t;
    int v = (i < N) ? ((cnt[i] + 7) & ~7) : 0;
    s[t] = v;
    __syncthreads();
    for (int off = 1; off < 1024; off <<= 1) {
        int u = (t >= off) ? s[t - off] : 0;
        __syncthreads();
        s[t] += u;
        __syncthreads();
    }
    if (i < N) rowptr[i] = s[t] - v;
    if (t == 1023) partial[blockIdx.x] = s[1023];
}

__global__ __launch_bounds__(1024) void k_scan_partial(int* __restrict__ partial, int NB) {
    __shared__ int s[1024];
    int t = threadIdx.x;
    int v = (t < NB) ? partial[t] : 0;
    s[t] = v;
    __syncthreads();
    for (int off = 1; off < 1024; off <<= 1) {
        int u = (t >= off) ? s[t - off] : 0;
        __syncthreads();
        s[t] += u;
        __syncthreads();
    }
    if (t < NB) partial[t] = s[t] - v;
}

// finalize rowptr8, dinv, write sentinel N into pad slots, rowptr8[N] by last thread
__global__ void k_finalize(int* __restrict__ rowptr, const int* __restrict__ partial,
                           const int* __restrict__ cnt, float* __restrict__ dinv,
                           int* __restrict__ col, int N, int E) {
    int i = blockIdx.x * 256 + threadIdx.x;
    if (i < N) {
        int rp = rowptr[i] + partial[i >> 10];
        rowptr[i] = rp;
        int deg = cnt[i];
        int deg8 = (deg + 7) & ~7;
        dinv[i] = rsqrtf((float)deg + 1.0f);
        for (int k = deg; k < deg8; ++k) col[rp + k] = N;   // zero-row sentinel
        if (i == N - 1) rowptr[N] = rp + deg8;
    }
}

__global__ void k_fill(const int* __restrict__ src, const int* __restrict__ dst,
                       const int* __restrict__ rowptr, const int* __restrict__ pos,
                       int* __restrict__ col, int E) {
    int e = blockIdx.x * 256 + threadIdx.x;
    if (e < E) col[rowptr[dst[e]] + pos[e]] = src[e];
}

// ---------------- W[128,128] fp32 -> W^T bf16 (both weights, one launch) ----------------
__global__ void k_wt2(const float* __restrict__ W1, const float* __restrict__ W2,
                      ushort* __restrict__ WT1, ushort* __restrict__ WT2) {
    int b = blockIdx.x, k = threadIdx.x;
    if (b < 128) WT1[b * 128 + k] = f2bf(W1[k * 128 + b]);
    else         WT2[(b - 128) * 128 + k] = f2bf(W2[k * 128 + (b - 128)]);
}

// -------- MFMA GEMM: H'[r] = dinv[r] * (X[r,:] @ W)  (bf16 out, pre-scaled) --------
template <bool F32IN>
__global__ __launch_bounds__(256) void k_gemm(const void* __restrict__ Xin,
                                              const ushort* __restrict__ WT,
                                              const float* __restrict__ dinv,
                                              ushort* __restrict__ H, int N) {
    __shared__ ushort sX[64 * 128];      // 16 KB
    __shared__ ushort sW[128 * 128];     // 32 KB
    char* sXb = (char*)sX;
    char* sWb = (char*)sW;

    int t = threadIdx.x;
    int w = t >> 6, lane = t & 63;
    int cl = lane & 15, kq = lane >> 4;
    int base = blockIdx.x * 64;

    // ---- stage W^T (rows c=0..127 of 256B, swizzled) ----
    const short8* Wg = (const short8*)WT;
#pragma unroll
    for (int k = 0; k < 8; ++k) {
        int idx = t + k * 256;                        // 0..2047 short8s
        int c = idx >> 4, ch = idx & 15;
        *(short8*)(sWb + c * 256 + ((ch * 16) ^ ((c & 7) << 4))) = Wg[idx];
    }

    // ---- stage X tile (rows base..base+63) ----
    if constexpr (F32IN) {
        const float4* X4 = (const float4*)Xin;
        size_t lim = (size_t)N * 32 - 1;
#pragma unroll
        for (int k = 0; k < 8; ++k) {
            int idx = t + k * 256;                    // 64 rows x 32 f4
            size_t gi = (size_t)base * 32 + idx;
            float4 v = X4[gi < lim ? gi : lim];
            ushort4 o;
            o.x = f2bf(v.x); o.y = f2bf(v.y); o.z = f2bf(v.z); o.w = f2bf(v.w);
            int row = idx >> 5, b8 = (idx & 31) * 8;
            *(ushort4*)(sXb + row * 256 + (b8 ^ ((row & 7) << 4))) = o;
        }
    } else {
        const short8* X8 = (const short8*)Xin;
        size_t lim = (size_t)N * 16 - 1;
#pragma unroll
        for (int k = 0; k < 4; ++k) {
            int idx = t + k * 256;                    // 64 rows x 16 s8
            size_t gi = (size_t)base * 16 + idx;
            short8 v = X8[gi < lim ? gi : lim];
            int row = idx >> 4, b16 = (idx & 15) * 16;
            *(short8*)(sXb + row * 256 + (b16 ^ ((row & 7) << 4))) = v;
        }
    }
    __syncthreads();

    // ---- X fragments ----
    int rl = w * 16 + cl;
    short8 b0, b1, b2, b3;
#pragma unroll
    for (int kt = 0; kt < 4; ++kt) {
        short8 v = *(const short8*)(sXb + rl * 256 + ((kt * 64 + kq * 16) ^ ((rl & 7) << 4)));
        if (kt == 0) b0 = v; else if (kt == 1) b1 = v; else if (kt == 2) b2 = v; else b3 = v;
    }

    int r = base + rl;
    bool ok = r < N;
    float di = dinv[min(r, N - 1)];
#pragma unroll
    for (int nt = 0; nt < 8; ++nt) {
        int c = nt * 16 + cl;                          // WT row = W col
        int sw = (c & 7) << 4;
        f32x4 acc = {0.f, 0.f, 0.f, 0.f};
        acc = __builtin_amdgcn_mfma_f32_16x16x32_bf16(
            *(const short8*)(sWb + c * 256 + ((0 * 64 + kq * 16) ^ sw)), b0, acc, 0, 0, 0);
        acc = __builtin_amdgcn_mfma_f32_16x16x32_bf16(
            *(const short8*)(sWb + c * 256 + ((1 * 64 + kq * 16) ^ sw)), b1, acc, 0, 0, 0);
        acc = __builtin_amdgcn_mfma_f32_16x16x32_bf16(
            *(const short8*)(sWb + c * 256 + ((2 * 64 + kq * 16) ^ sw)), b2, acc, 0, 0, 0);
        acc = __builtin_amdgcn_mfma_f32_16x16x32_bf16(
            *(const short8*)(sWb + c * 256 + ((3 * 64 + kq * 16) ^ sw)), b3, acc, 0, 0, 0);
        if (ok) {
            ushort4 o;
            o.x = f2bf(acc[0] * di); o.y = f2bf(acc[1] * di);
            o.z = f2bf(acc[2] * di); o.w = f2bf(acc[3] * di);
            *(ushort4*)(H + (size_t)r * 128 + nt * 16 + kq * 4) = o;
        }
    }
}

// ------- aggregate(pre-scaled bf16 h') + bias + ReLU + LN -------
// 2 nodes/wave (32 lanes each, uint2 = 4 features/lane), pad-8 rows (no clamps),
// 32-bit gather offsets; halves exec-mask-diverge on their own deg8.
__global__ __launch_bounds__(256) void k_agg(const uint2* __restrict__ H2,  // (N+1) rows x 32 uint2
                                             const int* __restrict__ rowptr, // rounded-8
                                             const int* __restrict__ col,
                                             const float* __restrict__ dinv,
                                             const float* __restrict__ bias,
                                             const float* __restrict__ gamma,
                                             const float* __restrict__ beta,
                                             float* __restrict__ outf,
                                             uint2* __restrict__ outb,
                                             int N) {
    int wave = threadIdx.x >> 6;
    int lane = threadIdx.x & 63;
    int half = lane >> 5;
    int l = lane & 31;                      // features 4l..4l+3
    int node = blockIdx.x * 8 + wave * 2 + half;
    bool valid = node < N;
    int nodec = valid ? node : N - 1;

    float di = dinv[nodec];
    uint2 hs = H2[(uint)nodec * 32u + (uint)l];
    float ax = bflo(hs.x), ay = bfhi(hs.x);
    float az = bflo(hs.y), aw = bfhi(hs.y);

    int beg = rowptr[nodec];
    int deg8 = rowptr[nodec + 1] - beg;     // multiple of 8, own count
    const int* cp = col + beg;

    for (int i = 0; i < deg8; i += 8) {
        int s0 = cp[i + 0], s1 = cp[i + 1], s2 = cp[i + 2], s3 = cp[i + 3];
        int s4 = cp[i + 4], s5 = cp[i + 5], s6 = cp[i + 6], s7 = cp[i + 7];
        uint2 u0 = H2[(uint)s0 * 32u + (uint)l];
        uint2 u1 = H2[(uint)s1 * 32u + (uint)l];
        uint2 u2 = H2[(uint)s2 * 32u + (uint)l];
        uint2 u3 = H2[(uint)s3 * 32u + (uint)l];
        uint2 u4 = H2[(uint)s4 * 32u + (uint)l];
        uint2 u5 = H2[(uint)s5 * 32u + (uint)l];
        uint2 u6 = H2[(uint)s6 * 32u + (uint)l];
        uint2 u7 = H2[(uint)s7 * 32u + (uint)l];
        ax += bflo(u0.x); ay += bfhi(u0.x); az += bflo(u0.y); aw += bfhi(u0.y);
        ax += bflo(u1.x); ay += bfhi(u1.x); az += bflo(u1.y); aw += bfhi(u1.y);
        ax += bflo(u2.x); ay += bfhi(u2.x); az += bflo(u2.y); aw += bfhi(u2.y);
        ax += bflo(u3.x); ay += bfhi(u3.x); az += bflo(u3.y); aw += bfhi(u3.y);
        ax += bflo(u4.x); ay += bfhi(u4.x); az += bflo(u4.y); aw += bfhi(u4.y);
        ax += bflo(u5.x); ay += bfhi(u5.x); az += bflo(u5.y); aw += bfhi(u5.y);
        ax += bflo(u6.x); ay += bfhi(u6.x); az += bflo(u6.y); aw += bfhi(u6.y);
        ax += bflo(u7.x); ay += bfhi(u7.x); az += bflo(u7.y); aw += bfhi(u7.y);
    }

    float4 bb = ((const float4*)bias)[l];
    float a0 = fmaxf(fmaf(ax, di, bb.x), 0.f);
    float a1 = fmaxf(fmaf(ay, di, bb.y), 0.f);
    float a2 = fmaxf(fmaf(az, di, bb.z), 0.f);
    float a3 = fmaxf(fmaf(aw, di, bb.w), 0.f);

    float s1 = a0 + a1 + a2 + a3;
    float s2 = a0 * a0 + a1 * a1 + a2 * a2 + a3 * a3;
#pragma unroll
    for (int off = 16; off >= 1; off >>= 1) {   // width-32 butterfly (stays in half)
        s1 += __shfl_xor(s1, off);
        s2 += __shfl_xor(s2, off);
    }
    float mu = s1 * (1.f / 128.f);
    float var = s2 * (1.f / 128.f) - mu * mu;
    float rs = rsqrtf(var + LN_EPS);

    float4 g = ((const float4*)gamma)[l];
    float4 be = ((const float4*)beta)[l];
    float o0 = (a0 - mu) * rs * g.x + be.x;
    float o1 = (a1 - mu) * rs * g.y + be.y;
    float o2 = (a2 - mu) * rs * g.z + be.z;
    float o3 = (a3 - mu) * rs * g.w + be.w;

    if (!valid) return;
    if (outf) {
        ((float4*)outf)[(size_t)node * 32 + l] = make_float4(o0, o1, o2, o3);
    } else {
        uint2 o;
        o.x = (uint)f2bf(o0) | ((uint)f2bf(o1) << 16);
        o.y = (uint)f2bf(o2) | ((uint)f2bf(o3) << 16);
        outb[(size_t)node * 32 + l] = o;
    }
}

// ---------------- launch ----------------
extern "C" void kernel_launch(void* const* d_in, const int* in_sizes, int n_in,
                              void* d_out, int out_size, void* d_ws, size_t ws_size,
                              hipStream_t stream) {
    const float* x  = (const float*)d_in[0];
    const int*   ei = (const int*)d_in[1];
    const float* W1 = (const float*)d_in[2];
    const float* b1 = (const float*)d_in[3];
    const float* W2 = (const float*)d_in[4];
    const float* b2 = (const float*)d_in[5];
    const float* g1 = (const float*)d_in[6];
    const float* be1 = (const float*)d_in[7];
    const float* g2 = (const float*)d_in[8];
    const float* be2 = (const float*)d_in[9];

    int N = in_sizes[0] / FDIM;
    int E = in_sizes[1] / 2;
    const int* srcp = ei;
    const int* dstp = ei + E;
    float* out = (float*)d_out;

    char* w = (char*)d_ws;
    size_t off = 0;
    auto take = [&](size_t bytes) {
        void* p = w + off;
        off = (off + bytes + 255) & ~(size_t)255;
        return p;
    };
    ushort* hb   = (ushort*)take((size_t)(N + 1) * FDIM * sizeof(ushort)); // h' + zero row N
    ushort* WT1  = (ushort*)take(128 * 128 * sizeof(ushort));
    ushort* WT2  = (ushort*)take(128 * 128 * sizeof(ushort));
    int* cnt     = (int*)take((size_t)N * sizeof(int));
    int* rowptr  = (int*)take((size_t)(N + 1) * sizeof(int));
    int* pos     = (int*)take((size_t)E * sizeof(int));
    int* colb    = (int*)take((size_t)(E + 7 * (size_t)N + 8) * sizeof(int)); // pad-8
    float* dinv  = (float*)take((size_t)N * sizeof(float));
    int* partial = (int*)take(1024 * sizeof(int));
    (void)ws_size;

    int NB = (N + 1023) >> 10;

    // zero cnt, zero sentinel row N of hb
    hipMemsetAsync(cnt, 0, (size_t)N * sizeof(int), stream);
    hipMemsetAsync(hb + (size_t)N * FDIM, 0, FDIM * sizeof(ushort), stream);

    // CSR build (pad-8; shared by both layers)
    k_count<<<(E + 255) / 256, 256, 0, stream>>>(dstp, cnt, pos, E);
    k_scan_block<<<NB, 1024, 0, stream>>>(cnt, rowptr, partial, N);
    k_scan_partial<<<1, 1024, 0, stream>>>(partial, NB);
    k_finalize<<<(N + 255) / 256, 256, 0, stream>>>(rowptr, partial, cnt, dinv, colb, N, E);
    k_fill<<<(E + 255) / 256, 256, 0, stream>>>(srcp, dstp, rowptr, pos, colb, E);

    // weights -> W^T bf16
    k_wt2<<<256, 128, 0, stream>>>(W1, W2, WT1, WT2);

    // layer 1: gemm (fp32 in, convert + dinv-scale fused) -> agg (bf16 out into d_out)
    k_gemm<true><<<(N + 63) / 64, 256, 0, stream>>>(x, WT1, dinv, hb, N);
    k_agg<<<(N + 7) / 8, 256, 0, stream>>>((const uint2*)hb, rowptr, colb, dinv,
                                           b1, g1, be1, nullptr, (uint2*)d_out, N);
    // layer 2: gemm reads bf16 from d_out, agg writes final fp32 d_out
    k_gemm<false><<<(N + 63) / 64, 256, 0, stream>>>(d_out, WT2, dinv, hb, N);
    k_agg<<<(N + 7) / 8, 256, 0, stream>>>((const uint2*)hb, rowptr, colb, dinv,
                                           b2, g2, be2, out, nullptr, N);
}

// Round 9
// 260.563 us; speedup vs baseline: 1.3975x; 1.0347x over previous
//
#include <hip/hip_runtime.h>

#define FDIM 128
#define LN_EPS 1e-5f

typedef short short8 __attribute__((ext_vector_type(8)));
typedef float f32x4 __attribute__((ext_vector_type(4)));

__device__ __forceinline__ ushort f2bf(float f) {
    uint u = __float_as_uint(f);
    u += 0x7fff + ((u >> 16) & 1);      // RNE
    return (ushort)(u >> 16);
}
__device__ __forceinline__ float bflo(uint u) { return __uint_as_float(u << 16); }
__device__ __forceinline__ float bfhi(uint u) { return __uint_as_float(u & 0xffff0000u); }

// ---------------- CSR build (pad-8 rows; count+pos16, fill reads pos16) ----------------
__global__ void k_count(const int* __restrict__ dst, int* __restrict__ cnt,
                        ushort* __restrict__ pos, int E) {
    int e = blockIdx.x * 256 + threadIdx.x;
    if (e < E) pos[e] = (ushort)atomicAdd(&cnt[dst[e]], 1);
}

// scan over ROUNDED counts -> rowptr8
__global__ __launch_bounds__(1024) void k_scan_block(const int* __restrict__ cnt,
                                                     int* __restrict__ rowptr,
                                                     int* __restrict__ partial, int N) {
    __shared__ int s[1024];
    int t = threadIdx.x;
    int i = blockIdx.x * 1024 + t;
    int v = (i < N) ? ((cnt[i] + 7) & ~7) : 0;
    s[t] = v;
    __syncthreads();
    for (int off = 1; off < 1024; off <<= 1) {
        int u = (t >= off) ? s[t - off] : 0;
        __syncthreads();
        s[t] += u;
        __syncthreads();
    }
    if (i < N) rowptr[i] = s[t] - v;
    if (t == 1023) partial[blockIdx.x] = s[1023];
}

__global__ __launch_bounds__(1024) void k_scan_partial(int* __restrict__ partial, int NB) {
    __shared__ int s[1024];
    int t = threadIdx.x;
    int v = (t < NB) ? partial[t] : 0;
    s[t] = v;
    __syncthreads();
    for (int off = 1; off < 1024; off <<= 1) {
        int u = (t >= off) ? s[t - off] : 0;
        __syncthreads();
        s[t] += u;
        __syncthreads();
    }
    if (t < NB) partial[t] = s[t] - v;
}

// finalize rowptr8, dinv, pad-slot sentinels, rowptr8[N]
__global__ void k_finalize(int* __restrict__ rowptr, const int* __restrict__ partial,
                           const int* __restrict__ cnt, float* __restrict__ dinv,
                           int* __restrict__ col, int N, int E) {
    int i = blockIdx.x * 256 + threadIdx.x;
    if (i < N) {
        int rp = rowptr[i] + partial[i >> 10];
        rowptr[i] = rp;
        int deg = cnt[i];
        int deg8 = (deg + 7) & ~7;
        dinv[i] = rsqrtf((float)deg + 1.0f);
        for (int k = deg; k < deg8; ++k) col[rp + k] = N;   // zero-row sentinel
        if (i == N - 1) rowptr[N] = rp + deg8;
    }
}

// ---------------- W[128,128] fp32 -> W^T bf16 (both weights, one launch) ----------------
__global__ void k_wt2(const float* __restrict__ W1, const float* __restrict__ W2,
                      ushort* __restrict__ WT1, ushort* __restrict__ WT2) {
    int b = blockIdx.x, k = threadIdx.x;
    if (b < 128) WT1[b * 128 + k] = f2bf(W1[k * 128 + b]);
    else         WT2[(b - 128) * 128 + k] = f2bf(W2[k * 128 + (b - 128)]);
}

// -------- GEMM body: H'[r] = dinv[r] * (X[r,:] @ W)  (bf16 out, pre-scaled) --------
template <bool F32IN>
__device__ __forceinline__ void gemm_body(char* sXb, char* sWb,
                                          const void* __restrict__ Xin,
                                          const ushort* __restrict__ WT,
                                          const float* __restrict__ dinv,
                                          ushort* __restrict__ H, int N, int bid) {
    int t = threadIdx.x;
    int w = t >> 6, lane = t & 63;
    int cl = lane & 15, kq = lane >> 4;
    int base = bid * 64;

    // ---- stage W^T (rows c=0..127 of 256B, swizzled) ----
    const short8* Wg = (const short8*)WT;
#pragma unroll
    for (int k = 0; k < 8; ++k) {
        int idx = t + k * 256;                        // 0..2047 short8s
        int c = idx >> 4, ch = idx & 15;
        *(short8*)(sWb + c * 256 + ((ch * 16) ^ ((c & 7) << 4))) = Wg[idx];
    }

    // ---- stage X tile (rows base..base+63) ----
    if constexpr (F32IN) {
        const float4* X4 = (const float4*)Xin;
        size_t lim = (size_t)N * 32 - 1;
#pragma unroll
        for (int k = 0; k < 8; ++k) {
            int idx = t + k * 256;                    // 64 rows x 32 f4
            size_t gi = (size_t)base * 32 + idx;
            float4 v = X4[gi < lim ? gi : lim];
            ushort4 o;
            o.x = f2bf(v.x); o.y = f2bf(v.y); o.z = f2bf(v.z); o.w = f2bf(v.w);
            int row = idx >> 5, b8 = (idx & 31) * 8;
            *(ushort4*)(sXb + row * 256 + (b8 ^ ((row & 7) << 4))) = o;
        }
    } else {
        const short8* X8 = (const short8*)Xin;
        size_t lim = (size_t)N * 16 - 1;
#pragma unroll
        for (int k = 0; k < 4; ++k) {
            int idx = t + k * 256;                    // 64 rows x 16 s8
            size_t gi = (size_t)base * 16 + idx;
            short8 v = X8[gi < lim ? gi : lim];
            int row = idx >> 4, b16 = (idx & 15) * 16;
            *(short8*)(sXb + row * 256 + (b16 ^ ((row & 7) << 4))) = v;
        }
    }
    __syncthreads();

    // ---- X fragments ----
    int rl = w * 16 + cl;
    short8 b0, b1, b2, b3;
#pragma unroll
    for (int kt = 0; kt < 4; ++kt) {
        short8 v = *(const short8*)(sXb + rl * 256 + ((kt * 64 + kq * 16) ^ ((rl & 7) << 4)));
        if (kt == 0) b0 = v; else if (kt == 1) b1 = v; else if (kt == 2) b2 = v; else b3 = v;
    }

    int r = base + rl;
    bool ok = r < N;
    float di = dinv[min(r, N - 1)];
#pragma unroll
    for (int nt = 0; nt < 8; ++nt) {
        int c = nt * 16 + cl;                          // WT row = W col
        int sw = (c & 7) << 4;
        f32x4 acc = {0.f, 0.f, 0.f, 0.f};
        acc = __builtin_amdgcn_mfma_f32_16x16x32_bf16(
            *(const short8*)(sWb + c * 256 + ((0 * 64 + kq * 16) ^ sw)), b0, acc, 0, 0, 0);
        acc = __builtin_amdgcn_mfma_f32_16x16x32_bf16(
            *(const short8*)(sWb + c * 256 + ((1 * 64 + kq * 16) ^ sw)), b1, acc, 0, 0, 0);
        acc = __builtin_amdgcn_mfma_f32_16x16x32_bf16(
            *(const short8*)(sWb + c * 256 + ((2 * 64 + kq * 16) ^ sw)), b2, acc, 0, 0, 0);
        acc = __builtin_amdgcn_mfma_f32_16x16x32_bf16(
            *(const short8*)(sWb + c * 256 + ((3 * 64 + kq * 16) ^ sw)), b3, acc, 0, 0, 0);
        if (ok) {
            ushort4 o;
            o.x = f2bf(acc[0] * di); o.y = f2bf(acc[1] * di);
            o.z = f2bf(acc[2] * di); o.w = f2bf(acc[3] * di);
            *(ushort4*)(H + (size_t)r * 128 + nt * 16 + kq * 4) = o;
        }
    }
}

// standalone gemm (layer 2)
template <bool F32IN>
__global__ __launch_bounds__(256) void k_gemm(const void* __restrict__ Xin,
                                              const ushort* __restrict__ WT,
                                              const float* __restrict__ dinv,
                                              ushort* __restrict__ H, int N) {
    __shared__ ushort sX[64 * 128];
    __shared__ ushort sW[128 * 128];
    gemm_body<F32IN>((char*)sX, (char*)sW, Xin, WT, dinv, H, N, blockIdx.x);
}

// -------- MEGA: blocks [0,ngemm) = gemm1 (fp32 in), blocks [ngemm,..) = fill --------
// gemm1 and fill are independent (gemm needs finalize's dinv; fill needs scan's rowptr)
// and both precede agg1 -> overlap them in one dispatch. gemm blocks first so they
// start immediately; fill is fabric-bound and tolerates the LDS-reduced occupancy.
__global__ __launch_bounds__(256) void k_mega(const void* __restrict__ Xin,
                                              const ushort* __restrict__ WT,
                                              const float* __restrict__ dinv,
                                              ushort* __restrict__ H, int N, int ngemm,
                                              const int* __restrict__ src,
                                              const int* __restrict__ dst,
                                              const int* __restrict__ rowptr,
                                              const ushort* __restrict__ pos,
                                              int* __restrict__ col, int E) {
    __shared__ ushort sX[64 * 128];
    __shared__ ushort sW[128 * 128];
    if (blockIdx.x < (uint)ngemm) {
        gemm_body<true>((char*)sX, (char*)sW, Xin, WT, dinv, H, N, blockIdx.x);
    } else {
        int e = (blockIdx.x - ngemm) * 256 + threadIdx.x;
        if (e < E) col[rowptr[dst[e]] + (int)pos[e]] = src[e];
    }
}

// ------- aggregate(pre-scaled bf16 h') + bias + ReLU + LN -------
// 4 nodes/wave (16 lanes each, uint4 = 8 features/lane), pad-8 rows (no clamps);
// quarters exec-mask-diverge on their own deg8.
__global__ __launch_bounds__(256) void k_agg(const uint4* __restrict__ H4,  // (N+1) rows x 16 uint4
                                             const int* __restrict__ rowptr, // rounded-8
                                             const int* __restrict__ col,
                                             const float* __restrict__ dinv,
                                             const float* __restrict__ bias,
                                             const float* __restrict__ gamma,
                                             const float* __restrict__ beta,
                                             float* __restrict__ outf,
                                             uint4* __restrict__ outb,
                                             int N) {
    int wave = threadIdx.x >> 6;
    int lane = threadIdx.x & 63;
    int q = lane >> 4;
    int l = lane & 15;                      // features 8l..8l+7
    int node = blockIdx.x * 16 + wave * 4 + q;
    bool valid = node < N;
    int nodec = valid ? node : N - 1;

    float di = dinv[nodec];
    uint4 hs = H4[(uint)nodec * 16u + (uint)l];
    float a0 = bflo(hs.x), a1 = bfhi(hs.x), a2 = bflo(hs.y), a3 = bfhi(hs.y);
    float a4 = bflo(hs.z), a5 = bfhi(hs.z), a6 = bflo(hs.w), a7 = bfhi(hs.w);

    int beg = rowptr[nodec];
    int deg8 = rowptr[nodec + 1] - beg;     // multiple of 8, own count
    const int* cp = col + beg;

    for (int i = 0; i < deg8; i += 8) {
        int s0 = cp[i + 0], s1 = cp[i + 1], s2 = cp[i + 2], s3 = cp[i + 3];
        int s4 = cp[i + 4], s5 = cp[i + 5], s6 = cp[i + 6], s7 = cp[i + 7];
        uint4 u0 = H4[(uint)s0 * 16u + (uint)l];
        uint4 u1 = H4[(uint)s1 * 16u + (uint)l];
        uint4 u2 = H4[(uint)s2 * 16u + (uint)l];
        uint4 u3 = H4[(uint)s3 * 16u + (uint)l];
        uint4 u4 = H4[(uint)s4 * 16u + (uint)l];
        uint4 u5 = H4[(uint)s5 * 16u + (uint)l];
        uint4 u6 = H4[(uint)s6 * 16u + (uint)l];
        uint4 u7 = H4[(uint)s7 * 16u + (uint)l];
        a0 += bflo(u0.x); a1 += bfhi(u0.x); a2 += bflo(u0.y); a3 += bfhi(u0.y);
        a4 += bflo(u0.z); a5 += bfhi(u0.z); a6 += bflo(u0.w); a7 += bfhi(u0.w);
        a0 += bflo(u1.x); a1 += bfhi(u1.x); a2 += bflo(u1.y); a3 += bfhi(u1.y);
        a4 += bflo(u1.z); a5 += bfhi(u1.z); a6 += bflo(u1.w); a7 += bfhi(u1.w);
        a0 += bflo(u2.x); a1 += bfhi(u2.x); a2 += bflo(u2.y); a3 += bfhi(u2.y);
        a4 += bflo(u2.z); a5 += bfhi(u2.z); a6 += bflo(u2.w); a7 += bfhi(u2.w);
        a0 += bflo(u3.x); a1 += bfhi(u3.x); a2 += bflo(u3.y); a3 += bfhi(u3.y);
        a4 += bflo(u3.z); a5 += bfhi(u3.z); a6 += bflo(u3.w); a7 += bfhi(u3.w);
        a0 += bflo(u4.x); a1 += bfhi(u4.x); a2 += bflo(u4.y); a3 += bfhi(u4.y);
        a4 += bflo(u4.z); a5 += bfhi(u4.z); a6 += bflo(u4.w); a7 += bfhi(u4.w);
        a0 += bflo(u5.x); a1 += bfhi(u5.x); a2 += bflo(u5.y); a3 += bfhi(u5.y);
        a4 += bflo(u5.z); a5 += bfhi(u5.z); a6 += bflo(u5.w); a7 += bfhi(u5.w);
        a0 += bflo(u6.x); a1 += bfhi(u6.x); a2 += bflo(u6.y); a3 += bfhi(u6.y);
        a4 += bflo(u6.z); a5 += bfhi(u6.z); a6 += bflo(u6.w); a7 += bfhi(u6.w);
        a0 += bflo(u7.x); a1 += bfhi(u7.x); a2 += bflo(u7.y); a3 += bfhi(u7.y);
        a4 += bflo(u7.z); a5 += bfhi(u7.z); a6 += bflo(u7.w); a7 += bfhi(u7.w);
    }

    float4 bb0 = ((const float4*)bias)[2 * l];
    float4 bb1 = ((const float4*)bias)[2 * l + 1];
    a0 = fmaxf(fmaf(a0, di, bb0.x), 0.f);
    a1 = fmaxf(fmaf(a1, di, bb0.y), 0.f);
    a2 = fmaxf(fmaf(a2, di, bb0.z), 0.f);
    a3 = fmaxf(fmaf(a3, di, bb0.w), 0.f);
    a4 = fmaxf(fmaf(a4, di, bb1.x), 0.f);
    a5 = fmaxf(fmaf(a5, di, bb1.y), 0.f);
    a6 = fmaxf(fmaf(a6, di, bb1.z), 0.f);
    a7 = fmaxf(fmaf(a7, di, bb1.w), 0.f);

    float s1 = ((a0 + a1) + (a2 + a3)) + ((a4 + a5) + (a6 + a7));
    float s2 = ((a0 * a0 + a1 * a1) + (a2 * a2 + a3 * a3)) +
               ((a4 * a4 + a5 * a5) + (a6 * a6 + a7 * a7));
#pragma unroll
    for (int off = 8; off >= 1; off >>= 1) {    // width-16 butterfly (stays in quarter)
        s1 += __shfl_xor(s1, off);
        s2 += __shfl_xor(s2, off);
    }
    float mu = s1 * (1.f / 128.f);
    float var = s2 * (1.f / 128.f) - mu * mu;
    float rs = rsqrtf(var + LN_EPS);

    float4 g0 = ((const float4*)gamma)[2 * l];
    float4 g1 = ((const float4*)gamma)[2 * l + 1];
    float4 e0 = ((const float4*)beta)[2 * l];
    float4 e1 = ((const float4*)beta)[2 * l + 1];
    float o0 = (a0 - mu) * rs * g0.x + e0.x;
    float o1 = (a1 - mu) * rs * g0.y + e0.y;
    float o2 = (a2 - mu) * rs * g0.z + e0.z;
    float o3 = (a3 - mu) * rs * g0.w + e0.w;
    float o4 = (a4 - mu) * rs * g1.x + e1.x;
    float o5 = (a5 - mu) * rs * g1.y + e1.y;
    float o6 = (a6 - mu) * rs * g1.z + e1.z;
    float o7 = (a7 - mu) * rs * g1.w + e1.w;

    if (!valid) return;
    if (outf) {
        ((float4*)outf)[(size_t)node * 32 + 2 * l]     = make_float4(o0, o1, o2, o3);
        ((float4*)outf)[(size_t)node * 32 + 2 * l + 1] = make_float4(o4, o5, o6, o7);
    } else {
        uint4 o;
        o.x = (uint)f2bf(o0) | ((uint)f2bf(o1) << 16);
        o.y = (uint)f2bf(o2) | ((uint)f2bf(o3) << 16);
        o.z = (uint)f2bf(o4) | ((uint)f2bf(o5) << 16);
        o.w = (uint)f2bf(o6) | ((uint)f2bf(o7) << 16);
        outb[(size_t)node * 16 + l] = o;
    }
}

// ---------------- launch ----------------
extern "C" void kernel_launch(void* const* d_in, const int* in_sizes, int n_in,
                              void* d_out, int out_size, void* d_ws, size_t ws_size,
                              hipStream_t stream) {
    const float* x  = (const float*)d_in[0];
    const int*   ei = (const int*)d_in[1];
    const float* W1 = (const float*)d_in[2];
    const float* b1 = (const float*)d_in[3];
    const float* W2 = (const float*)d_in[4];
    const float* b2 = (const float*)d_in[5];
    const float* g1 = (const float*)d_in[6];
    const float* be1 = (const float*)d_in[7];
    const float* g2 = (const float*)d_in[8];
    const float* be2 = (const float*)d_in[9];

    int N = in_sizes[0] / FDIM;
    int E = in_sizes[1] / 2;
    const int* srcp = ei;
    const int* dstp = ei + E;
    float* out = (float*)d_out;

    char* w = (char*)d_ws;
    size_t off = 0;
    auto take = [&](size_t bytes) {
        void* p = w + off;
        off = (off + bytes + 255) & ~(size_t)255;
        return p;
    };
    ushort* hb   = (ushort*)take((size_t)(N + 1) * FDIM * sizeof(ushort)); // h' + zero row N
    ushort* WT1  = (ushort*)take(128 * 128 * sizeof(ushort));
    ushort* WT2  = (ushort*)take(128 * 128 * sizeof(ushort));
    int* cnt     = (int*)take((size_t)N * sizeof(int));
    int* rowptr  = (int*)take((size_t)(N + 1) * sizeof(int));
    ushort* pos  = (ushort*)take((size_t)E * sizeof(ushort));
    int* colb    = (int*)take((size_t)(E + 7 * (size_t)N + 8) * sizeof(int)); // pad-8
    float* dinv  = (float*)take((size_t)N * sizeof(float));
    int* partial = (int*)take(1024 * sizeof(int));
    (void)ws_size;

    int NB = (N + 1023) >> 10;
    int ngemm = (N + 63) / 64;
    int nfill = (E + 255) / 256;

    // zero cnt, zero sentinel row N of hb
    hipMemsetAsync(cnt, 0, (size_t)N * sizeof(int), stream);
    hipMemsetAsync(hb + (size_t)N * FDIM, 0, FDIM * sizeof(ushort), stream);

    // weights -> W^T bf16 (independent, first)
    k_wt2<<<256, 128, 0, stream>>>(W1, W2, WT1, WT2);

    // CSR build chain
    k_count<<<(E + 255) / 256, 256, 0, stream>>>(dstp, cnt, pos, E);
    k_scan_block<<<NB, 1024, 0, stream>>>(cnt, rowptr, partial, N);
    k_scan_partial<<<1, 1024, 0, stream>>>(partial, NB);
    k_finalize<<<(N + 255) / 256, 256, 0, stream>>>(rowptr, partial, cnt, dinv, colb, N, E);

    // MEGA: gemm1 (fp32 in, convert + dinv-scale fused) || fill
    k_mega<<<ngemm + nfill, 256, 0, stream>>>(x, WT1, dinv, hb, N, ngemm,
                                              srcp, dstp, rowptr, pos, colb, E);

    // layer 1 agg (bf16 out into d_out front)
    k_agg<<<(N + 15) / 16, 256, 0, stream>>>((const uint4*)hb, rowptr, colb, dinv,
                                             b1, g1, be1, nullptr, (uint4*)d_out, N);
    // layer 2: gemm reads bf16 from d_out, agg writes final fp32 d_out
    k_gemm<false><<<ngemm, 256, 0, stream>>>(d_out, WT2, dinv, hb, N);
    k_agg<<<(N + 15) / 16, 256, 0, stream>>>((const uint4*)hb, rowptr, colb, dinv,
                                             b2, g2, be2, out, nullptr, N);
}

// Round 11
// 260.545 us; speedup vs baseline: 1.3976x; 1.0001x over previous
//
#include <hip/hip_runtime.h>

#define FDIM 128
#define LN_EPS 1e-5f
#define NXCD 8

typedef short short8 __attribute__((ext_vector_type(8)));
typedef float f32x4 __attribute__((ext_vector_type(4)));

__device__ __forceinline__ ushort f2bf(float f) {
    uint u = __float_as_uint(f);
    u += 0x7fff + ((u >> 16) & 1);      // RNE
    return (ushort)(u >> 16);
}
__device__ __forceinline__ float bflo(uint u) { return __uint_as_float(u << 16); }
__device__ __forceinline__ float bfhi(uint u) { return __uint_as_float(u & 0xffff0000u); }

// physical XCD of this wave: hwreg(20,0,32) = HW_REG_XCC_ID on gfx940+/gfx950 [m09]
__device__ __forceinline__ uint xcc_id() {
    uint x;
    asm volatile("s_getreg_b32 %0, hwreg(20, 0, 32)" : "=s"(x));
    return x & (NXCD - 1);
}

// ---------------- CSR build: XCD-local atomic count + recorded (x,slot) ----------------
// partial[x][n] counted ONLY by waves physically on XCD x with workgroup-scope
// atomics (retire in local L2 -> no device-scope fabric-RMW wall). The (x,slot)
// pair is recorded per edge, so fill is a pure gather+scatter (no atomic) and
// correctness does NOT depend on block->XCD placement in any later dispatch.
__global__ void k_count(const int* __restrict__ dst, uint* __restrict__ partial,
                        ushort* __restrict__ pos, int N, int E) {
    int e = blockIdx.x * 256 + threadIdx.x;
    uint x = xcc_id();
    if (e < E) {
        uint slot = __hip_atomic_fetch_add(&partial[(size_t)x * N + dst[e]], 1u,
                                           __ATOMIC_RELAXED, __HIP_MEMORY_SCOPE_WORKGROUP);
        pos[e] = (ushort)((x << 13) | (slot & 0x1FFFu));
    }
}

// scan over ROUNDED total counts (sum of 8 partials) -> rowptr8
__global__ __launch_bounds__(1024) void k_scan_block(const uint* __restrict__ partial,
                                                     int* __restrict__ rowptr,
                                                     int* __restrict__ partialscan, int N) {
    __shared__ int s[1024];
    int t = threadIdx.x;
    int i = blockIdx.x * 1024 + t;
    int v = 0;
    if (i < N) {
        int deg = 0;
#pragma unroll
        for (int x = 0; x < NXCD; ++x) deg += (int)partial[(size_t)x * N + i];
        v = (deg + 7) & ~7;
    }
    s[t] = v;
    __syncthreads();
    for (int off = 1; off < 1024; off <<= 1) {
        int u = (t >= off) ? s[t - off] : 0;
        __syncthreads();
        s[t] += u;
        __syncthreads();
    }
    if (i < N) rowptr[i] = s[t] - v;
    if (t == 1023) partialscan[blockIdx.x] = s[1023];
}

__global__ __launch_bounds__(1024) void k_scan_partial(int* __restrict__ partialscan, int NB) {
    __shared__ int s[1024];
    int t = threadIdx.x;
    int v = (t < NB) ? partialscan[t] : 0;
    s[t] = v;
    __syncthreads();
    for (int off = 1; off < 1024; off <<= 1) {
        int u = (t >= off) ? s[t - off] : 0;
        __syncthreads();
        s[t] += u;
        __syncthreads();
    }
    if (t < NB) partialscan[t] = s[t] - v;
}

// finalize: absolute rowptr8, per-(XCD,node) slot BASES (overwrite partial in place),
// dinv, pad-slot sentinels, rowptr8[N]
__global__ void k_finalize(int* __restrict__ rowptr, const int* __restrict__ partialscan,
                           uint* __restrict__ partial, float* __restrict__ dinv,
                           int* __restrict__ col, int N, int E) {
    int i = blockIdx.x * 256 + threadIdx.x;
    if (i < N) {
        int rp = rowptr[i] + partialscan[i >> 10];
        rowptr[i] = rp;
        int run = rp, deg = 0;
#pragma unroll
        for (int x = 0; x < NXCD; ++x) {
            uint c = partial[(size_t)x * N + i];
            partial[(size_t)x * N + i] = (uint)run;   // base for (XCD x, node i)
            run += (int)c;
            deg += (int)c;
        }
        int deg8 = (deg + 7) & ~7;
        dinv[i] = rsqrtf((float)deg + 1.0f);
        for (int k = deg; k < deg8; ++k) col[rp + k] = N;   // zero-row sentinel
        if (i == N - 1) rowptr[N] = rp + deg8;
    }
}

// ---------------- W[128,128] fp32 -> W^T bf16 (both weights, one launch) ----------------
__global__ void k_wt2(const float* __restrict__ W1, const float* __restrict__ W2,
                      ushort* __restrict__ WT1, ushort* __restrict__ WT2) {
    int b = blockIdx.x, k = threadIdx.x;
    if (b < 128) WT1[b * 128 + k] = f2bf(W1[k * 128 + b]);
    else         WT2[(b - 128) * 128 + k] = f2bf(W2[k * 128 + (b - 128)]);
}

// -------- GEMM body: H'[r] = dinv[r] * (X[r,:] @ W)  (bf16 out, pre-scaled) --------
template <bool F32IN>
__device__ __forceinline__ void gemm_body(char* sXb, char* sWb,
                                          const void* __restrict__ Xin,
                                          const ushort* __restrict__ WT,
                                          const float* __restrict__ dinv,
                                          ushort* __restrict__ H, int N, int bid) {
    int t = threadIdx.x;
    int w = t >> 6, lane = t & 63;
    int cl = lane & 15, kq = lane >> 4;
    int base = bid * 64;

    // ---- stage W^T (rows c=0..127 of 256B, swizzled) ----
    const short8* Wg = (const short8*)WT;
#pragma unroll
    for (int k = 0; k < 8; ++k) {
        int idx = t + k * 256;                        // 0..2047 short8s
        int c = idx >> 4, ch = idx & 15;
        *(short8*)(sWb + c * 256 + ((ch * 16) ^ ((c & 7) << 4))) = Wg[idx];
    }

    // ---- stage X tile (rows base..base+63) ----
    if constexpr (F32IN) {
        const float4* X4 = (const float4*)Xin;
        size_t lim = (size_t)N * 32 - 1;
#pragma unroll
        for (int k = 0; k < 8; ++k) {
            int idx = t + k * 256;                    // 64 rows x 32 f4
            size_t gi = (size_t)base * 32 + idx;
            float4 v = X4[gi < lim ? gi : lim];
            ushort4 o;
            o.x = f2bf(v.x); o.y = f2bf(v.y); o.z = f2bf(v.z); o.w = f2bf(v.w);
            int row = idx >> 5, b8 = (idx & 31) * 8;
            *(ushort4*)(sXb + row * 256 + (b8 ^ ((row & 7) << 4))) = o;
        }
    } else {
        const short8* X8 = (const short8*)Xin;
        size_t lim = (size_t)N * 16 - 1;
#pragma unroll
        for (int k = 0; k < 4; ++k) {
            int idx = t + k * 256;                    // 64 rows x 16 s8
            size_t gi = (size_t)base * 16 + idx;
            short8 v = X8[gi < lim ? gi : lim];
            int row = idx >> 4, b16 = (idx & 15) * 16;
            *(short8*)(sXb + row * 256 + (b16 ^ ((row & 7) << 4))) = v;
        }
    }
    __syncthreads();

    // ---- X fragments ----
    int rl = w * 16 + cl;
    short8 b0, b1, b2, b3;
#pragma unroll
    for (int kt = 0; kt < 4; ++kt) {
        short8 v = *(const short8*)(sXb + rl * 256 + ((kt * 64 + kq * 16) ^ ((rl & 7) << 4)));
        if (kt == 0) b0 = v; else if (kt == 1) b1 = v; else if (kt == 2) b2 = v; else b3 = v;
    }

    int r = base + rl;
    bool ok = r < N;
    float di = dinv[min(r, N - 1)];
#pragma unroll
    for (int nt = 0; nt < 8; ++nt) {
        int c = nt * 16 + cl;                          // WT row = W col
        int sw = (c & 7) << 4;
        f32x4 acc = {0.f, 0.f, 0.f, 0.f};
        acc = __builtin_amdgcn_mfma_f32_16x16x32_bf16(
            *(const short8*)(sWb + c * 256 + ((0 * 64 + kq * 16) ^ sw)), b0, acc, 0, 0, 0);
        acc = __builtin_amdgcn_mfma_f32_16x16x32_bf16(
            *(const short8*)(sWb + c * 256 + ((1 * 64 + kq * 16) ^ sw)), b1, acc, 0, 0, 0);
        acc = __builtin_amdgcn_mfma_f32_16x16x32_bf16(
            *(const short8*)(sWb + c * 256 + ((2 * 64 + kq * 16) ^ sw)), b2, acc, 0, 0, 0);
        acc = __builtin_amdgcn_mfma_f32_16x16x32_bf16(
            *(const short8*)(sWb + c * 256 + ((3 * 64 + kq * 16) ^ sw)), b3, acc, 0, 0, 0);
        if (ok) {
            ushort4 o;
            o.x = f2bf(acc[0] * di); o.y = f2bf(acc[1] * di);
            o.z = f2bf(acc[2] * di); o.w = f2bf(acc[3] * di);
            *(ushort4*)(H + (size_t)r * 128 + nt * 16 + kq * 4) = o;
        }
    }
}

// standalone gemm (layer 2)
template <bool F32IN>
__global__ __launch_bounds__(256) void k_gemm(const void* __restrict__ Xin,
                                              const ushort* __restrict__ WT,
                                              const float* __restrict__ dinv,
                                              ushort* __restrict__ H, int N) {
    __shared__ ushort sX[64 * 128];
    __shared__ ushort sW[128 * 128];
    gemm_body<F32IN>((char*)sX, (char*)sW, Xin, WT, dinv, H, N, blockIdx.x);
}

// -------- MEGA: blocks [0,ngemm) = gemm1 (fp32 in), rest = fill --------
// fill: slot = base[x][dst] + recorded local slot -> pure gather+scatter, no atomic.
__global__ __launch_bounds__(256) void k_mega(const void* __restrict__ Xin,
                                              const ushort* __restrict__ WT,
                                              const float* __restrict__ dinv,
                                              ushort* __restrict__ H, int N, int ngemm,
                                              const int* __restrict__ src,
                                              const int* __restrict__ dst,
                                              const uint* __restrict__ basep, // = partial (bases)
                                              const ushort* __restrict__ pos,
                                              int* __restrict__ col, int E) {
    __shared__ ushort sX[64 * 128];
    __shared__ ushort sW[128 * 128];
    if (blockIdx.x < (uint)ngemm) {
        gemm_body<true>((char*)sX, (char*)sW, Xin, WT, dinv, H, N, blockIdx.x);
    } else {
        int e = (blockIdx.x - ngemm) * 256 + threadIdx.x;
        if (e < E) {
            int d = dst[e];
            uint u = pos[e];
            uint x = u >> 13, p = u & 0x1FFFu;
            col[basep[(size_t)x * N + d] + p] = src[e];
        }
    }
}

// ------- aggregate(pre-scaled bf16 h') + bias + ReLU + LN -------
// 4 nodes/wave (16 lanes each, uint4 = 8 features/lane), pad-8 rows (no clamps);
// quarters exec-mask-diverge on their own deg8.
__global__ __launch_bounds__(256) void k_agg(const uint4* __restrict__ H4,  // (N+1) rows x 16 uint4
                                             const int* __restrict__ rowptr, // rounded-8
                                             const int* __restrict__ col,
                                             const float* __restrict__ dinv,
                                             const float* __restrict__ bias,
                                             const float* __restrict__ gamma,
                                             const float* __restrict__ beta,
                                             float* __restrict__ outf,
                                             uint4* __restrict__ outb,
                                             int N) {
    int wave = threadIdx.x >> 6;
    int lane = threadIdx.x & 63;
    int q = lane >> 4;
    int l = lane & 15;                      // features 8l..8l+7
    int node = blockIdx.x * 16 + wave * 4 + q;
    bool valid = node < N;
    int nodec = valid ? node : N - 1;

    float di = dinv[nodec];
    uint4 hs = H4[(uint)nodec * 16u + (uint)l];
    float a0 = bflo(hs.x), a1 = bfhi(hs.x), a2 = bflo(hs.y), a3 = bfhi(hs.y);
    float a4 = bflo(hs.z), a5 = bfhi(hs.z), a6 = bflo(hs.w), a7 = bfhi(hs.w);

    int beg = rowptr[nodec];
    int deg8 = rowptr[nodec + 1] - beg;     // multiple of 8, own count
    const int* cp = col + beg;

    for (int i = 0; i < deg8; i += 8) {
        int s0 = cp[i + 0], s1 = cp[i + 1], s2 = cp[i + 2], s3 = cp[i + 3];
        int s4 = cp[i + 4], s5 = cp[i + 5], s6 = cp[i + 6], s7 = cp[i + 7];
        uint4 u0 = H4[(uint)s0 * 16u + (uint)l];
        uint4 u1 = H4[(uint)s1 * 16u + (uint)l];
        uint4 u2 = H4[(uint)s2 * 16u + (uint)l];
        uint4 u3 = H4[(uint)s3 * 16u + (uint)l];
        uint4 u4 = H4[(uint)s4 * 16u + (uint)l];
        uint4 u5 = H4[(uint)s5 * 16u + (uint)l];
        uint4 u6 = H4[(uint)s6 * 16u + (uint)l];
        uint4 u7 = H4[(uint)s7 * 16u + (uint)l];
        a0 += bflo(u0.x); a1 += bfhi(u0.x); a2 += bflo(u0.y); a3 += bfhi(u0.y);
        a4 += bflo(u0.z); a5 += bfhi(u0.z); a6 += bflo(u0.w); a7 += bfhi(u0.w);
        a0 += bflo(u1.x); a1 += bfhi(u1.x); a2 += bflo(u1.y); a3 += bfhi(u1.y);
        a4 += bflo(u1.z); a5 += bfhi(u1.z); a6 += bflo(u1.w); a7 += bfhi(u1.w);
        a0 += bflo(u2.x); a1 += bfhi(u2.x); a2 += bflo(u2.y); a3 += bfhi(u2.y);
        a4 += bflo(u2.z); a5 += bfhi(u2.z); a6 += bflo(u2.w); a7 += bfhi(u2.w);
        a0 += bflo(u3.x); a1 += bfhi(u3.x); a2 += bflo(u3.y); a3 += bfhi(u3.y);
        a4 += bflo(u3.z); a5 += bfhi(u3.z); a6 += bflo(u3.w); a7 += bfhi(u3.w);
        a0 += bflo(u4.x); a1 += bfhi(u4.x); a2 += bflo(u4.y); a3 += bfhi(u4.y);
        a4 += bflo(u4.z); a5 += bfhi(u4.z); a6 += bflo(u4.w); a7 += bfhi(u4.w);
        a0 += bflo(u5.x); a1 += bfhi(u5.x); a2 += bflo(u5.y); a3 += bfhi(u5.y);
        a4 += bflo(u5.z); a5 += bfhi(u5.z); a6 += bflo(u5.w); a7 += bfhi(u5.w);
        a0 += bflo(u6.x); a1 += bfhi(u6.x); a2 += bflo(u6.y); a3 += bfhi(u6.y);
        a4 += bflo(u6.z); a5 += bfhi(u6.z); a6 += bflo(u6.w); a7 += bfhi(u6.w);
        a0 += bflo(u7.x); a1 += bfhi(u7.x); a2 += bflo(u7.y); a3 += bfhi(u7.y);
        a4 += bflo(u7.z); a5 += bfhi(u7.z); a6 += bflo(u7.w); a7 += bfhi(u7.w);
    }

    float4 bb0 = ((const float4*)bias)[2 * l];
    float4 bb1 = ((const float4*)bias)[2 * l + 1];
    a0 = fmaxf(fmaf(a0, di, bb0.x), 0.f);
    a1 = fmaxf(fmaf(a1, di, bb0.y), 0.f);
    a2 = fmaxf(fmaf(a2, di, bb0.z), 0.f);
    a3 = fmaxf(fmaf(a3, di, bb0.w), 0.f);
    a4 = fmaxf(fmaf(a4, di, bb1.x), 0.f);
    a5 = fmaxf(fmaf(a5, di, bb1.y), 0.f);
    a6 = fmaxf(fmaf(a6, di, bb1.z), 0.f);
    a7 = fmaxf(fmaf(a7, di, bb1.w), 0.f);

    float s1 = ((a0 + a1) + (a2 + a3)) + ((a4 + a5) + (a6 + a7));
    float s2 = ((a0 * a0 + a1 * a1) + (a2 * a2 + a3 * a3)) +
               ((a4 * a4 + a5 * a5) + (a6 * a6 + a7 * a7));
#pragma unroll
    for (int off = 8; off >= 1; off >>= 1) {    // width-16 butterfly (stays in quarter)
        s1 += __shfl_xor(s1, off);
        s2 += __shfl_xor(s2, off);
    }
    float mu = s1 * (1.f / 128.f);
    float var = s2 * (1.f / 128.f) - mu * mu;
    float rs = rsqrtf(var + LN_EPS);

    float4 g0 = ((const float4*)gamma)[2 * l];
    float4 g1 = ((const float4*)gamma)[2 * l + 1];
    float4 e0 = ((const float4*)beta)[2 * l];
    float4 e1 = ((const float4*)beta)[2 * l + 1];
    float o0 = (a0 - mu) * rs * g0.x + e0.x;
    float o1 = (a1 - mu) * rs * g0.y + e0.y;
    float o2 = (a2 - mu) * rs * g0.z + e0.z;
    float o3 = (a3 - mu) * rs * g0.w + e0.w;
    float o4 = (a4 - mu) * rs * g1.x + e1.x;
    float o5 = (a5 - mu) * rs * g1.y + e1.y;
    float o6 = (a6 - mu) * rs * g1.z + e1.z;
    float o7 = (a7 - mu) * rs * g1.w + e1.w;

    if (!valid) return;
    if (outf) {
        ((float4*)outf)[(size_t)node * 32 + 2 * l]     = make_float4(o0, o1, o2, o3);
        ((float4*)outf)[(size_t)node * 32 + 2 * l + 1] = make_float4(o4, o5, o6, o7);
    } else {
        uint4 o;
        o.x = (uint)f2bf(o0) | ((uint)f2bf(o1) << 16);
        o.y = (uint)f2bf(o2) | ((uint)f2bf(o3) << 16);
        o.z = (uint)f2bf(o4) | ((uint)f2bf(o5) << 16);
        o.w = (uint)f2bf(o6) | ((uint)f2bf(o7) << 16);
        outb[(size_t)node * 16 + l] = o;
    }
}

// ---------------- launch ----------------
extern "C" void kernel_launch(void* const* d_in, const int* in_sizes, int n_in,
                              void* d_out, int out_size, void* d_ws, size_t ws_size,
                              hipStream_t stream) {
    const float* x  = (const float*)d_in[0];
    const int*   ei = (const int*)d_in[1];
    const float* W1 = (const float*)d_in[2];
    const float* b1 = (const float*)d_in[3];
    const float* W2 = (const float*)d_in[4];
    const float* b2 = (const float*)d_in[5];
    const float* g1 = (const float*)d_in[6];
    const float* be1 = (const float*)d_in[7];
    const float* g2 = (const float*)d_in[8];
    const float* be2 = (const float*)d_in[9];

    int N = in_sizes[0] / FDIM;
    int E = in_sizes[1] / 2;
    const int* srcp = ei;
    const int* dstp = ei + E;
    float* out = (float*)d_out;

    char* w = (char*)d_ws;
    size_t off = 0;
    auto take = [&](size_t bytes) {
        void* p = w + off;
        off = (off + bytes + 255) & ~(size_t)255;
        return p;
    };
    ushort* hb    = (ushort*)take((size_t)(N + 1) * FDIM * sizeof(ushort)); // h' + zero row N
    ushort* WT1   = (ushort*)take(128 * 128 * sizeof(ushort));
    ushort* WT2   = (ushort*)take(128 * 128 * sizeof(ushort));
    uint* partial = (uint*)take((size_t)NXCD * N * sizeof(uint));  // counts -> slot bases
    int* rowptr   = (int*)take((size_t)(N + 1) * sizeof(int));
    ushort* pos   = (ushort*)take((size_t)E * sizeof(ushort));     // (xcd<<13)|slot per edge
    int* colb     = (int*)take((size_t)(E + 7 * (size_t)N + 1024) * sizeof(int)); // pad-8 + slack
    float* dinv   = (float*)take((size_t)N * sizeof(float));
    int* pscan    = (int*)take(1024 * sizeof(int));
    (void)ws_size;

    int NB = (N + 1023) >> 10;
    int ngemm = (N + 63) / 64;
    int nfill = (E + 255) / 256;

    // zero partial histograms, zero sentinel row N of hb
    hipMemsetAsync(partial, 0, (size_t)NXCD * N * sizeof(uint), stream);
    hipMemsetAsync(hb + (size_t)N * FDIM, 0, FDIM * sizeof(ushort), stream);

    // weights -> W^T bf16 (independent, first)
    k_wt2<<<256, 128, 0, stream>>>(W1, W2, WT1, WT2);

    // CSR build chain (XCD-local atomics + recorded slots)
    k_count<<<(E + 255) / 256, 256, 0, stream>>>(dstp, partial, pos, N, E);
    k_scan_block<<<NB, 1024, 0, stream>>>(partial, rowptr, pscan, N);
    k_scan_partial<<<1, 1024, 0, stream>>>(pscan, NB);
    k_finalize<<<(N + 255) / 256, 256, 0, stream>>>(rowptr, pscan, partial, dinv, colb, N, E);

    // MEGA: gemm1 (fp32 in, convert + dinv-scale fused) || fill (no atomics)
    k_mega<<<ngemm + nfill, 256, 0, stream>>>(x, WT1, dinv, hb, N, ngemm,
                                              srcp, dstp, partial, pos, colb, E);

    // layer 1 agg (bf16 out into d_out front)
    k_agg<<<(N + 15) / 16, 256, 0, stream>>>((const uint4*)hb, rowptr, colb, dinv,
                                             b1, g1, be1, nullptr, (uint4*)d_out, N);
    // layer 2: gemm reads bf16 from d_out, agg writes final fp32 d_out
    k_gemm<false><<<ngemm, 256, 0, stream>>>(d_out, WT2, dinv, hb, N);
    k_agg<<<(N + 15) / 16, 256, 0, stream>>>((const uint4*)hb, rowptr, colb, dinv,
                                             b2, g2, be2, out, nullptr, N);
}

// Round 12
// 221.665 us; speedup vs baseline: 1.6427x; 1.1754x over previous
//
#include <hip/hip_runtime.h>

#define FDIM 128
#define LN_EPS 1e-5f
#define BSH 9              // 512 nodes per bucket; nbk = ceil(N/512) <= 256 for N<=131072
#define EPB 2048           // edges per block in bucket passes

typedef short short8 __attribute__((ext_vector_type(8)));
typedef float f32x4 __attribute__((ext_vector_type(4)));

__device__ __forceinline__ ushort f2bf(float f) {
    uint u = __float_as_uint(f);
    u += 0x7fff + ((u >> 16) & 1);      // RNE
    return (ushort)(u >> 16);
}
__device__ __forceinline__ float bflo(uint u) { return __uint_as_float(u << 16); }
__device__ __forceinline__ float bfhi(uint u) { return __uint_as_float(u & 0xffff0000u); }

// ---------------- bucketed CSR build (no global atomics) ----------------

// A: per-block 196-bucket LDS histogram of dst>>BSH -> mat[blk][bkt]
__global__ __launch_bounds__(256) void k_bcount(const int* __restrict__ dst,
                                                uint* __restrict__ mat, int nbk, int E) {
    __shared__ uint cnt[512];
    int t = threadIdx.x;
    for (int i = t; i < nbk; i += 256) cnt[i] = 0;
    __syncthreads();
    int base = blockIdx.x * EPB, end = min(base + EPB, E);
    for (int e = base + t; e < end; e += 256)
        atomicAdd(&cnt[(uint)dst[e] >> BSH], 1u);
    __syncthreads();
    for (int i = t; i < nbk; i += 256) mat[(size_t)blockIdx.x * nbk + i] = cnt[i];
}

// B: column-exclusive scan of mat (per bucket), bucket totals
__global__ __launch_bounds__(1024) void k_colscan(uint* __restrict__ mat,
                                                  uint* __restrict__ btot, int nbk, int nblk) {
    __shared__ uint s[1024];
    int b = blockIdx.x, t = threadIdx.x;
    uint run = 0;
    for (int base = 0; base < nblk; base += 1024) {
        int i = base + t;
        uint v = (i < nblk) ? mat[(size_t)i * nbk + b] : 0;
        s[t] = v;
        __syncthreads();
        for (int off = 1; off < 1024; off <<= 1) {
            uint u = (t >= off) ? s[t - off] : 0;
            __syncthreads();
            s[t] += u;
            __syncthreads();
        }
        if (i < nblk) mat[(size_t)i * nbk + b] = run + s[t] - v;   // exclusive within column
        run += s[1023];
        __syncthreads();
    }
    if (t == 0) btot[b] = run;
}

// C: scatter edges into bucket-contiguous ebuf, packed (dlocal<<17)|src
__global__ __launch_bounds__(256) void k_bscatter(const int* __restrict__ src,
                                                  const int* __restrict__ dst,
                                                  const uint* __restrict__ mat,
                                                  const uint* __restrict__ btot,
                                                  uint* __restrict__ ebuf, int nbk, int E) {
    __shared__ uint cur[512];
    __shared__ uint ps[256];
    int t = threadIdx.x;
    uint v = (t < nbk) ? btot[t] : 0;
    ps[t] = v;
    __syncthreads();
    for (int off = 1; off < 256; off <<= 1) {
        uint u = (t >= off) ? ps[t - off] : 0;
        __syncthreads();
        ps[t] += u;
        __syncthreads();
    }
    if (t < nbk) cur[t] = (ps[t] - v) + mat[(size_t)blockIdx.x * nbk + t];  // bbase + colpre
    __syncthreads();
    int base = blockIdx.x * EPB, end = min(base + EPB, E);
    for (int e = base + t; e < end; e += 256) {
        uint d = (uint)dst[e];
        uint off = atomicAdd(&cur[d >> BSH], 1u);
        ebuf[off] = ((d & 511u) << 17) | (uint)src[e];   // src < 2^17
    }
}

// D1: per-bucket node histogram -> deg, dinv, padded bucket total
__global__ __launch_bounds__(256) void k_bdeg(const uint* __restrict__ ebuf,
                                              const uint* __restrict__ btot,
                                              int* __restrict__ deg, float* __restrict__ dinv,
                                              uint* __restrict__ padtot, int N, int nbk) {
    __shared__ uint cnt[512];
    __shared__ uint ps[256];
    __shared__ uint begs;
    int b = blockIdx.x, t = threadIdx.x;
    for (int i = t; i < 512; i += 256) cnt[i] = 0;
    uint v = (t < nbk) ? btot[t] : 0;
    ps[t] = v;
    __syncthreads();
    for (int off = 1; off < 256; off <<= 1) {
        uint u = (t >= off) ? ps[t - off] : 0;
        __syncthreads();
        ps[t] += u;
        __syncthreads();
    }
    if (t == b) begs = ps[t] - v;
    __syncthreads();
    uint beg = begs, cn = btot[b];
    for (uint i = t; i < cn; i += 256) atomicAdd(&cnt[ebuf[beg + i] >> 17], 1u);
    __syncthreads();
    int n0 = b << BSH;
    uint loc = 0;
    for (int i = t; i < 512; i += 256) {
        int n = n0 + i;
        if (n < N) {
            uint dg = cnt[i];
            deg[n] = (int)dg;
            dinv[n] = rsqrtf((float)dg + 1.0f);
            loc += (dg + 7u) & ~7u;
        }
    }
    ps[t] = loc;
    __syncthreads();
    for (int off = 128; off >= 1; off >>= 1) {
        if (t < off) ps[t] += ps[t + off];
        __syncthreads();
    }
    if (t == 0) padtot[b] = ps[0];
}

// D2 body: per-bucket rowptr8 + sentinels + LDS-cursor fill of col
__device__ __forceinline__ void bfill_body(const uint* __restrict__ ebuf,
                                           const uint* __restrict__ btot,
                                           const uint* __restrict__ padtot,
                                           const int* __restrict__ deg,
                                           int* __restrict__ rowptr, int* __restrict__ col,
                                           int N, int nbk, int b) {
    __shared__ uint ps[256];
    __shared__ uint lrp[512];
    __shared__ uint curf[512];
    __shared__ uint sc0, sc1;
    int t = threadIdx.x;
    // beg = exclusive prefix of btot at b
    uint v = (t < nbk) ? btot[t] : 0;
    ps[t] = v;
    __syncthreads();
    for (int off = 1; off < 256; off <<= 1) {
        uint u = (t >= off) ? ps[t - off] : 0;
        __syncthreads();
        ps[t] += u;
        __syncthreads();
    }
    if (t == b) sc0 = ps[t] - v;
    __syncthreads();
    // base = exclusive prefix of padtot at b; rowptr[N] from last bucket
    uint w = (t < nbk) ? padtot[t] : 0;
    ps[t] = w;
    __syncthreads();
    for (int off = 1; off < 256; off <<= 1) {
        uint u = (t >= off) ? ps[t - off] : 0;
        __syncthreads();
        ps[t] += u;
        __syncthreads();
    }
    if (t == b) sc1 = ps[t] - w;
    if (b == nbk - 1 && t == nbk - 1) rowptr[N] = (int)ps[t];
    __syncthreads();
    uint beg = sc0, cn = btot[b], base = sc1;
    // node-level padded scan (512 nodes, 2 per thread)
    int n0 = b << BSH;
    int nA = n0 + 2 * t, nB = nA + 1;
    uint dA = (nA < N) ? (uint)deg[nA] : 0;
    uint dB = (nB < N) ? (uint)deg[nB] : 0;
    uint pA = (dA + 7u) & ~7u, pB = (dB + 7u) & ~7u;
    uint pair = pA + pB;
    ps[t] = pair;
    __syncthreads();
    for (int off = 1; off < 256; off <<= 1) {
        uint u = (t >= off) ? ps[t - off] : 0;
        __syncthreads();
        ps[t] += u;
        __syncthreads();
    }
    uint pex = ps[t] - pair;
    uint rA = base + pex, rB = rA + pA;
    lrp[2 * t] = rA; lrp[2 * t + 1] = rB;
    curf[2 * t] = rA; curf[2 * t + 1] = rB;
    if (nA < N) rowptr[nA] = (int)rA;
    if (nB < N) rowptr[nB] = (int)rB;
    if (nA < N) for (uint k = dA; k < pA; ++k) col[rA + k] = N;   // sentinels
    if (nB < N) for (uint k = dB; k < pB; ++k) col[rB + k] = N;
    __syncthreads();
    for (uint i = t; i < cn; i += 256) {
        uint e = ebuf[beg + i];
        uint p = atomicAdd(&curf[e >> 17], 1u);
        col[p] = (int)(e & 0x1FFFFu);
    }
}

// ---------------- W[128,128] fp32 -> W^T bf16 (both weights, one launch) ----------------
__global__ void k_wt2(const float* __restrict__ W1, const float* __restrict__ W2,
                      ushort* __restrict__ WT1, ushort* __restrict__ WT2) {
    int b = blockIdx.x, k = threadIdx.x;
    if (b < 128) WT1[b * 128 + k] = f2bf(W1[k * 128 + b]);
    else         WT2[(b - 128) * 128 + k] = f2bf(W2[k * 128 + (b - 128)]);
}

// -------- GEMM body: H'[r] = dinv[r] * (X[r,:] @ W)  (bf16 out, pre-scaled) --------
template <bool F32IN>
__device__ __forceinline__ void gemm_body(char* sXb, char* sWb,
                                          const void* __restrict__ Xin,
                                          const ushort* __restrict__ WT,
                                          const float* __restrict__ dinv,
                                          ushort* __restrict__ H, int N, int bid) {
    int t = threadIdx.x;
    int w = t >> 6, lane = t & 63;
    int cl = lane & 15, kq = lane >> 4;
    int base = bid * 64;

    const short8* Wg = (const short8*)WT;
#pragma unroll
    for (int k = 0; k < 8; ++k) {
        int idx = t + k * 256;
        int c = idx >> 4, ch = idx & 15;
        *(short8*)(sWb + c * 256 + ((ch * 16) ^ ((c & 7) << 4))) = Wg[idx];
    }

    if constexpr (F32IN) {
        const float4* X4 = (const float4*)Xin;
        size_t lim = (size_t)N * 32 - 1;
#pragma unroll
        for (int k = 0; k < 8; ++k) {
            int idx = t + k * 256;
            size_t gi = (size_t)base * 32 + idx;
            float4 v = X4[gi < lim ? gi : lim];
            ushort4 o;
            o.x = f2bf(v.x); o.y = f2bf(v.y); o.z = f2bf(v.z); o.w = f2bf(v.w);
            int row = idx >> 5, b8 = (idx & 31) * 8;
            *(ushort4*)(sXb + row * 256 + (b8 ^ ((row & 7) << 4))) = o;
        }
    } else {
        const short8* X8 = (const short8*)Xin;
        size_t lim = (size_t)N * 16 - 1;
#pragma unroll
        for (int k = 0; k < 4; ++k) {
            int idx = t + k * 256;
            size_t gi = (size_t)base * 16 + idx;
            short8 v = X8[gi < lim ? gi : lim];
            int row = idx >> 4, b16 = (idx & 15) * 16;
            *(short8*)(sXb + row * 256 + (b16 ^ ((row & 7) << 4))) = v;
        }
    }
    __syncthreads();

    int rl = w * 16 + cl;
    short8 b0, b1, b2, b3;
#pragma unroll
    for (int kt = 0; kt < 4; ++kt) {
        short8 v = *(const short8*)(sXb + rl * 256 + ((kt * 64 + kq * 16) ^ ((rl & 7) << 4)));
        if (kt == 0) b0 = v; else if (kt == 1) b1 = v; else if (kt == 2) b2 = v; else b3 = v;
    }

    int r = base + rl;
    bool ok = r < N;
    float di = dinv[min(r, N - 1)];
#pragma unroll
    for (int nt = 0; nt < 8; ++nt) {
        int c = nt * 16 + cl;
        int sw = (c & 7) << 4;
        f32x4 acc = {0.f, 0.f, 0.f, 0.f};
        acc = __builtin_amdgcn_mfma_f32_16x16x32_bf16(
            *(const short8*)(sWb + c * 256 + ((0 * 64 + kq * 16) ^ sw)), b0, acc, 0, 0, 0);
        acc = __builtin_amdgcn_mfma_f32_16x16x32_bf16(
            *(const short8*)(sWb + c * 256 + ((1 * 64 + kq * 16) ^ sw)), b1, acc, 0, 0, 0);
        acc = __builtin_amdgcn_mfma_f32_16x16x32_bf16(
            *(const short8*)(sWb + c * 256 + ((2 * 64 + kq * 16) ^ sw)), b2, acc, 0, 0, 0);
        acc = __builtin_amdgcn_mfma_f32_16x16x32_bf16(
            *(const short8*)(sWb + c * 256 + ((3 * 64 + kq * 16) ^ sw)), b3, acc, 0, 0, 0);
        if (ok) {
            ushort4 o;
            o.x = f2bf(acc[0] * di); o.y = f2bf(acc[1] * di);
            o.z = f2bf(acc[2] * di); o.w = f2bf(acc[3] * di);
            *(ushort4*)(H + (size_t)r * 128 + nt * 16 + kq * 4) = o;
        }
    }
}

// standalone gemm (layer 2)
template <bool F32IN>
__global__ __launch_bounds__(256) void k_gemm(const void* __restrict__ Xin,
                                              const ushort* __restrict__ WT,
                                              const float* __restrict__ dinv,
                                              ushort* __restrict__ H, int N) {
    __shared__ ushort sX[64 * 128];
    __shared__ ushort sW[128 * 128];
    gemm_body<F32IN>((char*)sX, (char*)sW, Xin, WT, dinv, H, N, blockIdx.x);
}

// -------- MEGA: blocks [0,ngemm) = gemm1 (fp32 in), blocks [ngemm,ngemm+nbk) = D2 fill --------
__global__ __launch_bounds__(256) void k_mega(const void* __restrict__ Xin,
                                              const ushort* __restrict__ WT,
                                              const float* __restrict__ dinv,
                                              ushort* __restrict__ H, int N, int ngemm,
                                              const uint* __restrict__ ebuf,
                                              const uint* __restrict__ btot,
                                              const uint* __restrict__ padtot,
                                              const int* __restrict__ deg,
                                              int* __restrict__ rowptr,
                                              int* __restrict__ col, int nbk) {
    __shared__ ushort sX[64 * 128];
    __shared__ ushort sW[128 * 128];
    if (blockIdx.x < (uint)ngemm) {
        gemm_body<true>((char*)sX, (char*)sW, Xin, WT, dinv, H, N, blockIdx.x);
    } else {
        bfill_body(ebuf, btot, padtot, deg, rowptr, col, N, nbk, blockIdx.x - ngemm);
    }
}

// ------- aggregate(pre-scaled bf16 h') + bias + ReLU + LN -------
__global__ __launch_bounds__(256) void k_agg(const uint4* __restrict__ H4,  // (N+1) rows x 16 uint4
                                             const int* __restrict__ rowptr, // rounded-8
                                             const int* __restrict__ col,
                                             const float* __restrict__ dinv,
                                             const float* __restrict__ bias,
                                             const float* __restrict__ gamma,
                                             const float* __restrict__ beta,
                                             float* __restrict__ outf,
                                             uint4* __restrict__ outb,
                                             int N) {
    int wave = threadIdx.x >> 6;
    int lane = threadIdx.x & 63;
    int q = lane >> 4;
    int l = lane & 15;
    int node = blockIdx.x * 16 + wave * 4 + q;
    bool valid = node < N;
    int nodec = valid ? node : N - 1;

    float di = dinv[nodec];
    uint4 hs = H4[(uint)nodec * 16u + (uint)l];
    float a0 = bflo(hs.x), a1 = bfhi(hs.x), a2 = bflo(hs.y), a3 = bfhi(hs.y);
    float a4 = bflo(hs.z), a5 = bfhi(hs.z), a6 = bflo(hs.w), a7 = bfhi(hs.w);

    int beg = rowptr[nodec];
    int deg8 = rowptr[nodec + 1] - beg;
    const int* cp = col + beg;

    for (int i = 0; i < deg8; i += 8) {
        int s0 = cp[i + 0], s1 = cp[i + 1], s2 = cp[i + 2], s3 = cp[i + 3];
        int s4 = cp[i + 4], s5 = cp[i + 5], s6 = cp[i + 6], s7 = cp[i + 7];
        uint4 u0 = H4[(uint)s0 * 16u + (uint)l];
        uint4 u1 = H4[(uint)s1 * 16u + (uint)l];
        uint4 u2 = H4[(uint)s2 * 16u + (uint)l];
        uint4 u3 = H4[(uint)s3 * 16u + (uint)l];
        uint4 u4 = H4[(uint)s4 * 16u + (uint)l];
        uint4 u5 = H4[(uint)s5 * 16u + (uint)l];
        uint4 u6 = H4[(uint)s6 * 16u + (uint)l];
        uint4 u7 = H4[(uint)s7 * 16u + (uint)l];
        a0 += bflo(u0.x); a1 += bfhi(u0.x); a2 += bflo(u0.y); a3 += bfhi(u0.y);
        a4 += bflo(u0.z); a5 += bfhi(u0.z); a6 += bflo(u0.w); a7 += bfhi(u0.w);
        a0 += bflo(u1.x); a1 += bfhi(u1.x); a2 += bflo(u1.y); a3 += bfhi(u1.y);
        a4 += bflo(u1.z); a5 += bfhi(u1.z); a6 += bflo(u1.w); a7 += bfhi(u1.w);
        a0 += bflo(u2.x); a1 += bfhi(u2.x); a2 += bflo(u2.y); a3 += bfhi(u2.y);
        a4 += bflo(u2.z); a5 += bfhi(u2.z); a6 += bflo(u2.w); a7 += bfhi(u2.w);
        a0 += bflo(u3.x); a1 += bfhi(u3.x); a2 += bflo(u3.y); a3 += bfhi(u3.y);
        a4 += bflo(u3.z); a5 += bfhi(u3.z); a6 += bflo(u3.w); a7 += bfhi(u3.w);
        a0 += bflo(u4.x); a1 += bfhi(u4.x); a2 += bflo(u4.y); a3 += bfhi(u4.y);
        a4 += bflo(u4.z); a5 += bfhi(u4.z); a6 += bflo(u4.w); a7 += bfhi(u4.w);
        a0 += bflo(u5.x); a1 += bfhi(u5.x); a2 += bflo(u5.y); a3 += bfhi(u5.y);
        a4 += bflo(u5.z); a5 += bfhi(u5.z); a6 += bflo(u5.w); a7 += bfhi(u5.w);
        a0 += bflo(u6.x); a1 += bfhi(u6.x); a2 += bflo(u6.y); a3 += bfhi(u6.y);
        a4 += bflo(u6.z); a5 += bfhi(u6.z); a6 += bflo(u6.w); a7 += bfhi(u6.w);
        a0 += bflo(u7.x); a1 += bfhi(u7.x); a2 += bflo(u7.y); a3 += bfhi(u7.y);
        a4 += bflo(u7.z); a5 += bfhi(u7.z); a6 += bflo(u7.w); a7 += bfhi(u7.w);
    }

    float4 bb0 = ((const float4*)bias)[2 * l];
    float4 bb1 = ((const float4*)bias)[2 * l + 1];
    a0 = fmaxf(fmaf(a0, di, bb0.x), 0.f);
    a1 = fmaxf(fmaf(a1, di, bb0.y), 0.f);
    a2 = fmaxf(fmaf(a2, di, bb0.z), 0.f);
    a3 = fmaxf(fmaf(a3, di, bb0.w), 0.f);
    a4 = fmaxf(fmaf(a4, di, bb1.x), 0.f);
    a5 = fmaxf(fmaf(a5, di, bb1.y), 0.f);
    a6 = fmaxf(fmaf(a6, di, bb1.z), 0.f);
    a7 = fmaxf(fmaf(a7, di, bb1.w), 0.f);

    float s1 = ((a0 + a1) + (a2 + a3)) + ((a4 + a5) + (a6 + a7));
    float s2 = ((a0 * a0 + a1 * a1) + (a2 * a2 + a3 * a3)) +
               ((a4 * a4 + a5 * a5) + (a6 * a6 + a7 * a7));
#pragma unroll
    for (int off = 8; off >= 1; off >>= 1) {
        s1 += __shfl_xor(s1, off);
        s2 += __shfl_xor(s2, off);
    }
    float mu = s1 * (1.f / 128.f);
    float var = s2 * (1.f / 128.f) - mu * mu;
    float rs = rsqrtf(var + LN_EPS);

    float4 g0 = ((const float4*)gamma)[2 * l];
    float4 g1 = ((const float4*)gamma)[2 * l + 1];
    float4 e0 = ((const float4*)beta)[2 * l];
    float4 e1 = ((const float4*)beta)[2 * l + 1];
    float o0 = (a0 - mu) * rs * g0.x + e0.x;
    float o1 = (a1 - mu) * rs * g0.y + e0.y;
    float o2 = (a2 - mu) * rs * g0.z + e0.z;
    float o3 = (a3 - mu) * rs * g0.w + e0.w;
    float o4 = (a4 - mu) * rs * g1.x + e1.x;
    float o5 = (a5 - mu) * rs * g1.y + e1.y;
    float o6 = (a6 - mu) * rs * g1.z + e1.z;
    float o7 = (a7 - mu) * rs * g1.w + e1.w;

    if (!valid) return;
    if (outf) {
        ((float4*)outf)[(size_t)node * 32 + 2 * l]     = make_float4(o0, o1, o2, o3);
        ((float4*)outf)[(size_t)node * 32 + 2 * l + 1] = make_float4(o4, o5, o6, o7);
    } else {
        uint4 o;
        o.x = (uint)f2bf(o0) | ((uint)f2bf(o1) << 16);
        o.y = (uint)f2bf(o2) | ((uint)f2bf(o3) << 16);
        o.z = (uint)f2bf(o4) | ((uint)f2bf(o5) << 16);
        o.w = (uint)f2bf(o6) | ((uint)f2bf(o7) << 16);
        outb[(size_t)node * 16 + l] = o;
    }
}

// ---------------- launch ----------------
extern "C" void kernel_launch(void* const* d_in, const int* in_sizes, int n_in,
                              void* d_out, int out_size, void* d_ws, size_t ws_size,
                              hipStream_t stream) {
    const float* x  = (const float*)d_in[0];
    const int*   ei = (const int*)d_in[1];
    const float* W1 = (const float*)d_in[2];
    const float* b1 = (const float*)d_in[3];
    const float* W2 = (const float*)d_in[4];
    const float* b2 = (const float*)d_in[5];
    const float* g1 = (const float*)d_in[6];
    const float* be1 = (const float*)d_in[7];
    const float* g2 = (const float*)d_in[8];
    const float* be2 = (const float*)d_in[9];

    int N = in_sizes[0] / FDIM;
    int E = in_sizes[1] / 2;
    const int* srcp = ei;
    const int* dstp = ei + E;
    float* out = (float*)d_out;

    char* w = (char*)d_ws;
    size_t off = 0;
    auto take = [&](size_t bytes) {
        void* p = w + off;
        off = (off + bytes + 255) & ~(size_t)255;
        return p;
    };
    int nbk  = (N + 511) >> BSH;                       // buckets (<=256 for N<=131k)
    int nblk = (E + EPB - 1) / EPB;                    // edge-pass blocks

    ushort* hb   = (ushort*)take((size_t)(N + 1) * FDIM * sizeof(ushort)); // h' + zero row N
    ushort* WT1  = (ushort*)take(128 * 128 * sizeof(ushort));
    ushort* WT2  = (ushort*)take(128 * 128 * sizeof(ushort));
    uint* mat    = (uint*)take((size_t)nblk * nbk * sizeof(uint));
    uint* btot   = (uint*)take((size_t)nbk * sizeof(uint));
    uint* padtot = (uint*)take((size_t)nbk * sizeof(uint));
    uint* ebuf   = (uint*)take((size_t)E * sizeof(uint));
    int* deg     = (int*)take((size_t)N * sizeof(int));
    int* rowptr  = (int*)take((size_t)(N + 1) * sizeof(int));
    int* colb    = (int*)take((size_t)(E + 7 * (size_t)N + 1024) * sizeof(int));
    float* dinv  = (float*)take((size_t)N * sizeof(float));
    (void)ws_size;

    int ngemm = (N + 63) / 64;

    // zero sentinel row N of hb
    hipMemsetAsync(hb + (size_t)N * FDIM, 0, FDIM * sizeof(ushort), stream);

    // weights -> W^T bf16
    k_wt2<<<256, 128, 0, stream>>>(W1, W2, WT1, WT2);

    // bucketed CSR build (no global atomics)
    k_bcount<<<nblk, 256, 0, stream>>>(dstp, mat, nbk, E);
    k_colscan<<<nbk, 1024, 0, stream>>>(mat, btot, nbk, nblk);
    k_bscatter<<<nblk, 256, 0, stream>>>(srcp, dstp, mat, btot, ebuf, nbk, E);
    k_bdeg<<<nbk, 256, 0, stream>>>(ebuf, btot, deg, dinv, padtot, N, nbk);

    // MEGA: gemm1 (fp32 in, convert + dinv-scale fused) || D2 bucket fill
    k_mega<<<ngemm + nbk, 256, 0, stream>>>(x, WT1, dinv, hb, N, ngemm,
                                            ebuf, btot, padtot, deg, rowptr, colb, nbk);

    // layer 1 agg (bf16 out into d_out front)
    k_agg<<<(N + 15) / 16, 256, 0, stream>>>((const uint4*)hb, rowptr, colb, dinv,
                                             b1, g1, be1, nullptr, (uint4*)d_out, N);
    // layer 2: gemm reads bf16 from d_out, agg writes final fp32 d_out
    k_gemm<false><<<ngemm, 256, 0, stream>>>(d_out, WT2, dinv, hb, N);
    k_agg<<<(N + 15) / 16, 256, 0, stream>>>((const uint4*)hb, rowptr, colb, dinv,
                                             b2, g2, be2, out, nullptr, N);
}